// Round 20
// baseline (1321.333 us; speedup 1.0000x reference)
//
#include <hip/hip_runtime.h>
#include <hip/hip_bf16.h>
#include <cstdint>

typedef float v4f __attribute__((ext_vector_type(4)));
typedef short v8s __attribute__((ext_vector_type(8)));
typedef unsigned short u16;

#define N_SEQ 2048
#define D_MODEL 512
#define N_LAYER 6
#define N_HEAD 8
#define D_HEAD 64
#define M_FEAT 266
#define M_PAD 288
#define M_ALLOC 384
#define FF_DIM 2048
#define BATCH 4
#define ROWS 8192
#define BHN 65536   // B*H*N

__device__ __forceinline__ float b2f(u16 u) {
  return __uint_as_float(((uint32_t)u) << 16);
}
__device__ __forceinline__ u16 f2b(float f) {
  union { __hip_bfloat16 h; u16 u; } c;
  c.h = __float2bfloat16(f);
  return c.u;
}
__device__ __forceinline__ float wave_sum(float v) {
#pragma unroll
  for (int o = 1; o < 64; o <<= 1) v += __shfl_xor(v, o);
  return v;
}
__device__ __forceinline__ float wave_max(float v) {
#pragma unroll
  for (int o = 1; o < 64; o <<= 1) v = fmaxf(v, __shfl_xor(v, o));
  return v;
}

// exact-erf gelu via Abramowitz-Stegun 7.1.26 (|erf err| <= 1.5e-7)
__device__ __forceinline__ float gelu_f(float x) {
  float ax = fabsf(x) * 0.70710678118f;
  float tt = __builtin_amdgcn_rcpf(fmaf(0.3275911f, ax, 1.0f));
  float poly = tt * fmaf(tt, fmaf(tt, fmaf(tt, fmaf(tt, 1.061405429f, -1.453152027f),
                                           1.421413741f), -0.284496736f), 0.254829592f);
  float er = 1.0f - poly * __expf(-ax * ax);
  er = copysignf(er, x);
  return 0.5f * x * (1.0f + er);
}

__device__ __forceinline__ void mfma_bf16(v4f& d, v8s a, v8s b) {
  asm volatile("v_mfma_f32_16x16x32_bf16 %0, %1, %2, %0" : "+v"(d) : "v"(a), "v"(b));
}

// async global->LDS, 16B per lane. LDS dest must be wave-linear (base + lane*16).
__device__ __forceinline__ void async16(const u16* g, u16* l) {
  __builtin_amdgcn_global_load_lds(
      (const __attribute__((address_space(1))) uint32_t*)g,
      (__attribute__((address_space(3))) uint32_t*)l, 16, 0, 0);
}

// ---------------------------------------------------------------------------
// gemm4s: 128x256 tile, BK=32, 512 threads (8 waves 2Mx4N, 64x64 each).
// Asymmetric dual ring: A 4 slots, B 3 slots; counted vmcnt(4). 80KB LDS.
// KTOT is compile-time -> K-loop FULLY UNROLLED: slot indices, staging
// branches and vmcnt selection all constant-fold.
// EPI: 0 = bf16 out; 3 = bf16 gelu(acc + bias); 5 = f32 split partial.
// ---------------------------------------------------------------------------
template <int EPI, int KSPLIT, int KTOT>
__global__ void __launch_bounds__(512, 4)
gemm4s(const u16* __restrict__ A, const u16* __restrict__ B,
       void* __restrict__ Cv, const float* __restrict__ bias,
       int ldc)
{
  extern __shared__ u16 lds[];
  const int t = threadIdx.x;
  const int lane = t & 63;
  const int w = t >> 6;
  const int wm = w >> 2;
  const int wn = w & 3;
  const int tiM = blockIdx.x << 7, tiN = blockIdx.y << 8;
  const int ks = (KSPLIT > 1) ? blockIdx.z : 0;
  constexpr int kchunk = KTOT / KSPLIT;
  constexpr int NT = kchunk >> 5;
  static_assert(NT >= 4, "pipeline needs >= 4 K-tiles");

  const int rr = lane & 15;
  const int kq = (lane >> 4) << 3;
  const int sw = ((rr >> 1) & 3) << 3;
  const int cr = kq ^ sw;

  const int srow = t >> 2;
  const int scol = (((t & 3) ^ ((srow >> 1) & 3)) << 3);
  const u16* Abase = A + (long long)(tiM + srow) * KTOT + scol + (long long)ks * kchunk;
  const u16* Bbase = B + (long long)(tiN + srow) * KTOT + scol + (long long)ks * kchunk;
  constexpr long long r128 = 128LL * KTOT;

  v4f acc[4][4] = {};

  auto stageA = [&](int s, int kt) {
    async16(Abase + (long long)kt * 32, &lds[s * 4096 + t * 8]);
  };
  auto stageB = [&](int s, int kt) {
    u16* d = &lds[16384 + s * 8192 + t * 8];
    async16(Bbase + (long long)kt * 32, d);
    async16(Bbase + (long long)kt * 32 + r128, d + 4096);
  };

  stageB(0, 0);
  stageA(0, 0);
  stageB(1, 1);
  stageA(1, 1);
  stageA(2, 2);
  asm volatile("s_waitcnt vmcnt(4)" ::: "memory");
  __builtin_amdgcn_s_barrier();

#pragma unroll
  for (int kt = 0; kt < NT; ++kt) {
    const int ab = (kt & 3) * 4096;          // compile-time per unrolled iter
    const int bb = 16384 + (kt % 3) * 8192;  // compile-time per unrolled iter
    if (kt + 2 < NT) stageB((kt + 2) % 3, kt + 2);
    if (kt + 3 < NT) stageA((kt + 3) & 3, kt + 3);
    v8s af[4], bf[4];
#pragma unroll
    for (int i = 0; i < 4; i++) {
      af[i] = *(const v8s*)&lds[ab + (wm * 64 + i * 16 + rr) * 32 + cr];
      bf[i] = *(const v8s*)&lds[bb + (wn * 64 + i * 16 + rr) * 32 + cr];
    }
    __builtin_amdgcn_s_setprio(1);
#pragma unroll
    for (int m = 0; m < 4; m++)
#pragma unroll
      for (int n = 0; n < 4; n++) mfma_bf16(acc[m][n], af[m], bf[n]);
    __builtin_amdgcn_s_setprio(0);
    if (kt + 1 < NT) {
      if (kt + 3 < NT)      asm volatile("s_waitcnt vmcnt(4)" ::: "memory");
      else if (kt + 2 < NT) asm volatile("s_waitcnt vmcnt(3)" ::: "memory");
      else                  asm volatile("s_waitcnt vmcnt(0)" ::: "memory");
      __builtin_amdgcn_s_barrier();
    }
  }

  __builtin_amdgcn_sched_barrier(0);
  asm volatile("s_nop 7\ns_nop 7\ns_nop 7");
  __builtin_amdgcn_sched_barrier(0);

  const int r4 = (lane >> 4) << 2;
  const int cc = lane & 15;
#pragma unroll
  for (int mf = 0; mf < 4; mf++)
#pragma unroll
    for (int nf = 0; nf < 4; nf++)
#pragma unroll
      for (int i = 0; i < 4; i++) {
        int row = tiM + wm * 64 + mf * 16 + r4 + i;
        int col = tiN + wn * 64 + nf * 16 + cc;
        float v = acc[mf][nf][i];
        if (EPI == 0) {
          ((u16*)Cv)[(long long)row * ldc + col] = f2b(v);
        } else if (EPI == 3) {
          ((u16*)Cv)[(long long)row * ldc + col] = f2b(gelu_f(v + bias[col]));
        } else {  // EPI == 5: f32 split partial
          ((float*)Cv)[((long long)ks * ROWS + row) * ldc + col] = v;
        }
      }
}

// ---------------------------------------------------------------------------
// ff2red_ln: x_new = x + sum of NSPLIT FF2 partials + b2; then LN(x_new).
// ---------------------------------------------------------------------------
template <bool LAST, int NSPLIT>
__global__ void ff2red_ln(const float* __restrict__ part, const float* __restrict__ bias,
                          float* __restrict__ x, const float* __restrict__ g,
                          const float* __restrict__ bvec, void* __restrict__ out)
{
  const int row = blockIdx.x * 4 + (threadIdx.x >> 6);
  const int lane = threadIdx.x & 63;
  const long long base = (long long)row * D_MODEL + lane * 8;
  v4f s0 = {}, s1 = {};
#pragma unroll
  for (int ks = 0; ks < NSPLIT; ks++) {
    const float* p = part + (long long)ks * (ROWS * 512LL) + base;
    s0 += *(const v4f*)p;
    s1 += *(const v4f*)(p + 4);
  }
  v4f b0 = *(const v4f*)(bias + lane * 8);
  v4f b1 = *(const v4f*)(bias + lane * 8 + 4);
  v4f x0 = *(const v4f*)(x + base) + s0 + b0;
  v4f x1 = *(const v4f*)(x + base + 4) + s1 + b1;
  if (!LAST) {
    *(v4f*)(x + base) = x0;
    *(v4f*)(x + base + 4) = x1;
  }
  float s = x0[0] + x0[1] + x0[2] + x0[3] + x1[0] + x1[1] + x1[2] + x1[3];
  float sq = x0[0]*x0[0] + x0[1]*x0[1] + x0[2]*x0[2] + x0[3]*x0[3]
           + x1[0]*x1[0] + x1[1]*x1[1] + x1[2]*x1[2] + x1[3]*x1[3];
  s = wave_sum(s);
  sq = wave_sum(sq);
  float mu = s * (1.0f / D_MODEL);
  float var = sq * (1.0f / D_MODEL) - mu * mu;
  float rstd = rsqrtf(var + 1e-5f);
  v4f g0 = *(const v4f*)(g + lane * 8), g1 = *(const v4f*)(g + lane * 8 + 4);
  v4f bb0 = *(const v4f*)(bvec + lane * 8), bb1 = *(const v4f*)(bvec + lane * 8 + 4);
  float y[8];
#pragma unroll
  for (int j = 0; j < 4; j++) y[j] = (x0[j] - mu) * rstd * g0[j] + bb0[j];
#pragma unroll
  for (int j = 0; j < 4; j++) y[4 + j] = (x1[j] - mu) * rstd * g1[j] + bb1[j];
  if (LAST) {
    float* op = (float*)out + base;
    v4f o0 = {y[0], y[1], y[2], y[3]}, o1 = {y[4], y[5], y[6], y[7]};
    *(v4f*)op = o0;
    *(v4f*)(op + 4) = o1;
  } else {
    u16* op = (u16*)out + base;
    alignas(16) u16 tmp[8];
#pragma unroll
    for (int j = 0; j < 8; j++) tmp[j] = f2b(y[j]);
    *(v8s*)op = *(v8s*)tmp;
  }
}

// ---------------------------------------------------------------------------
// gemm2: BM=128, BN in {64,128}.
// EPI: 5 = f32 split-K partial (stride M_PAD); 7 = max-only + fused atomicMax
// ---------------------------------------------------------------------------
template <int EPI, int BN, int KSPLIT>
__global__ void __launch_bounds__(256, 4)
gemm2(const u16* __restrict__ A, const u16* __restrict__ B,
      void* __restrict__ Cv, const float* __restrict__ bias,
      int K, int ldc, long long sA, long long sB, long long sC,
      float scale, int Ncap, int Mcap, unsigned int* __restrict__ gmax)
{
  __shared__ u16 As[2][128 * 32];
  __shared__ u16 Bs[2][BN * 32];
  __shared__ float smax[4];
  const int zz = blockIdx.z;
  const int z = (KSPLIT > 1) ? zz / KSPLIT : zz;
  const int ks = (KSPLIT > 1) ? zz % KSPLIT : 0;
  const int kchunk = K / KSPLIT;
  const u16* Ag = A + (long long)z * sA + ks * kchunk;
  const u16* Bg = B + (long long)z * sB + ks * kchunk;
  const int t = threadIdx.x;
  const int lane = t & 63;
  const int w = t >> 6;
  constexpr int NF = BN / 32;
  const int wm = (w >> 1) << 6;
  const int wn = (w & 1) * (BN / 2);
  const int tiM = blockIdx.x << 7, tiN = blockIdx.y * BN;

  const int srow = t >> 2;
  const int scol = (t & 3) << 3;
  const u16* Ap = Ag + (long long)(tiM + srow) * K + scol;
  const u16* Bp = Bg + (long long)(tiN + srow) * K + scol;
  const long long rstride = 64LL * K;

  const int rr = lane & 15;
  const int kc = (lane >> 4) << 3;

  v4f acc[4][NF] = {};

  const int nk = kchunk >> 5;
  auto stage = [&](int buf, int k0) {
    async16(Ap + k0, &As[buf][t * 8]);
    async16(Ap + k0 + rstride, &As[buf][t * 8 + 2048]);
    async16(Bp + k0, &Bs[buf][t * 8]);
    if (BN == 128) async16(Bp + k0 + rstride, &Bs[buf][t * 8 + 2048]);
  };

  stage(0, 0);
  __syncthreads();
  int cur = 0;
  for (int kt = 0; kt < nk; ++kt) {
    if (kt + 1 < nk) stage(cur ^ 1, (kt + 1) << 5);
    v8s af[4], bf[NF];
#pragma unroll
    for (int i = 0; i < 4; i++) af[i] = *(const v8s*)&As[cur][(wm + rr + i * 16) * 32 + kc];
#pragma unroll
    for (int i = 0; i < NF; i++) bf[i] = *(const v8s*)&Bs[cur][(wn + rr + i * 16) * 32 + kc];
#pragma unroll
    for (int fm = 0; fm < 4; fm++)
#pragma unroll
      for (int fn = 0; fn < NF; fn++)
        mfma_bf16(acc[fm][fn], af[fm], bf[fn]);
    __syncthreads();
    cur ^= 1;
  }

  __builtin_amdgcn_sched_barrier(0);
  asm volatile("s_nop 7\ns_nop 7\ns_nop 7");
  __builtin_amdgcn_sched_barrier(0);

  const int r4 = (lane >> 4) << 2;
  const int cc = lane & 15;
  float lmax = -3e38f;
#pragma unroll
  for (int fm = 0; fm < 4; fm++)
#pragma unroll
    for (int fn = 0; fn < NF; fn++)
#pragma unroll
      for (int i = 0; i < 4; i++) {
        int row = tiM + wm + fm * 16 + r4 + i;
        int col = tiN + wn + fn * 16 + cc;
        float v = acc[fm][fn][i];
        if (EPI == 5) {
          if (row < Mcap && col < Ncap)
            ((float*)Cv)[((long long)zz * M_PAD + row) * 64 + col] = v;
        } else if (EPI == 7) {
          if (col < M_FEAT) lmax = fmaxf(lmax, v * scale);
        }
      }

  if (EPI == 7) {
    lmax = wave_max(lmax);
    if (lane == 0) smax[w] = lmax;
    __syncthreads();
    if (t == 0) {
      float m = fmaxf(fmaxf(smax[0], smax[1]), fmaxf(smax[2], smax[3]));
      unsigned int u = __float_as_uint(m);
      unsigned int key = (u & 0x80000000u) ? ~u : (u | 0x80000000u);
      atomicMax(gmax, key);
    }
  }
}

// ---------------------------------------------------------------------------
// kf_gemm: transposed K-feature GEMM + fused exp epilogue (dd never stored).
// ---------------------------------------------------------------------------
__global__ void __launch_bounds__(384, 3)
kf_gemm(const u16* __restrict__ kr, const u16* __restrict__ proj,
        const float* __restrict__ diagk, const unsigned int* __restrict__ kmax,
        u16* __restrict__ kfT, float* __restrict__ part)
{
  __shared__ u16 As[2][288 * 32];   // proj rows m
  __shared__ u16 Bs[2][64 * 32];    // k_rot rows n
  __shared__ float sdg[64];
  const int ntile = blockIdx.x;     // 0..31
  const int bh = blockIdx.z;        // 0..31
  const int n0 = ntile << 6;
  const int t = threadIdx.x;
  const int lane = t & 63;
  const int w = t >> 6;             // 0..5
  const u16* Bg = kr + (long long)bh * (N_SEQ * 64) + (long long)n0 * 64;
  const int rr = lane & 15, kc = (lane >> 4) << 3;

  if (t < 64) sdg[t] = diagk[(long long)bh * N_SEQ + n0 + t];
  unsigned int kk = kmax[0];
  const float km = (kk & 0x80000000u) ? __uint_as_float(kk ^ 0x80000000u)
                                      : __uint_as_float(~kk);

  v4f acc[3][4] = {};
  auto stage = [&](int buf, int k0) {
#pragma unroll
    for (int j = 0; j < 3; j++) {
      int idx = j * 384 + t;        // proj rows 0..287
      async16(proj + (long long)(idx >> 2) * 64 + ((idx & 3) << 3) + k0,
              &As[buf][j * 3072 + t * 8]);
    }
    if (t < 256) async16(Bg + (long long)(t >> 2) * 64 + ((t & 3) << 3) + k0,
                         &Bs[buf][t * 8]);
  };

  stage(0, 0);
  __syncthreads();
  for (int kt = 0; kt < 2; ++kt) {
    if (kt == 0) stage(1, 32);
    v8s af[3], bf[4];
#pragma unroll
    for (int i = 0; i < 3; i++) af[i] = *(const v8s*)&As[kt][(w * 48 + i * 16 + rr) * 32 + kc];
#pragma unroll
    for (int i = 0; i < 4; i++) bf[i] = *(const v8s*)&Bs[kt][(i * 16 + rr) * 32 + kc];
#pragma unroll
    for (int fm = 0; fm < 3; fm++)
#pragma unroll
      for (int fn = 0; fn < 4; fn++)
        mfma_bf16(acc[fm][fn], af[fm], bf[fn]);
    __syncthreads();
  }

  __builtin_amdgcn_sched_barrier(0);
  asm volatile("s_nop 7\ns_nop 7\ns_nop 7");
  __builtin_amdgcn_sched_barrier(0);

  const int r4 = (lane >> 4) << 2;
  const int cc = lane & 15;
  const float sc = 0.35355339f;

#pragma unroll
  for (int fm = 0; fm < 3; fm++)
#pragma unroll
    for (int i = 0; i < 4; i++) {
      int m = w * 48 + fm * 16 + r4 + i;
      float s = 0.0f;
#pragma unroll
      for (int fn = 0; fn < 4; fn++) {
        float dd = acc[fm][fn][i] * sc;
        float kf = (m < M_FEAT)
            ? 0.06131389f * (__expf(dd - sdg[fn * 16 + cc] - km) + 1e-4f) : 0.0f;
        acc[fm][fn][i] = kf;
        s += kf;
        kfT[((long long)bh * M_ALLOC + m) * N_SEQ + n0 + fn * 16 + cc] = f2b(kf);
      }
#pragma unroll
      for (int o = 1; o < 16; o <<= 1) s += __shfl_xor(s, o);
      if (cc == 0) part[((long long)bh * M_PAD + m) * 32 + ntile] = s;
    }
}

// ksum reduce: f32 sum + bf16 copy (for the MFMA denominator in ddq_qf_o)
__global__ void ksumred(const float* __restrict__ part, float* __restrict__ ksum,
                        u16* __restrict__ ksumb)
{
  int i = blockIdx.x * 256 + threadIdx.x;  // 32*288
  if (i >= 32 * M_PAD) return;
  const float* p = part + (long long)i * 32;
  float s = 0.0f;
#pragma unroll
  for (int j = 0; j < 32; j += 4) {
    v4f v = *(const v4f*)(p + j);
    s += v[0] + v[1] + v[2] + v[3];
  }
  ksum[i] = s;
  ksumb[i] = f2b(s);
}

// ---------------------------------------------------------------------------
// gemm_small: BM=64, BN=64, BK=32, compile-time K (unrolled loop).
// EPI 2 = f32 residual += acc + bias.
// ---------------------------------------------------------------------------
template <int EPI, int K>
__global__ void __launch_bounds__(256, 6)
gemm_small(const u16* __restrict__ A, const u16* __restrict__ B,
           void* __restrict__ Cv, const float* __restrict__ bias,
           int ldc, long long sA, long long sB)
{
  __shared__ u16 As[2][64 * 32];
  __shared__ u16 Bs[2][64 * 32];
  const int z = blockIdx.z;
  const u16* Ag = A + (long long)z * sA;
  const u16* Bg = B + (long long)z * sB;
  const int t = threadIdx.x;
  const int lane = t & 63;
  const int w = t >> 6;
  const int wm = (w >> 1) << 5;
  const int wn = (w & 1) << 5;
  const int tiM = blockIdx.x << 6, tiN = blockIdx.y << 6;

  const int srow = t >> 2;
  const int scol = (t & 3) << 3;
  const u16* Ap = Ag + (long long)(tiM + srow) * K + scol;
  const u16* Bp = Bg + (long long)(tiN + srow) * K + scol;

  const int rr = lane & 15;
  const int kc = (lane >> 4) << 3;

  v4f acc[2][2] = {};

  constexpr int nk = K >> 5;
  auto stage = [&](int buf, int k0) {
    async16(Ap + k0, &As[buf][t * 8]);
    async16(Bp + k0, &Bs[buf][t * 8]);
  };

  stage(0, 0);
  __syncthreads();
#pragma unroll
  for (int kt = 0; kt < nk; ++kt) {
    const int cur = kt & 1;
    if (kt + 1 < nk) stage(cur ^ 1, (kt + 1) << 5);
    v8s af[2], bf[2];
#pragma unroll
    for (int i = 0; i < 2; i++) af[i] = *(const v8s*)&As[cur][(wm + rr + i * 16) * 32 + kc];
#pragma unroll
    for (int i = 0; i < 2; i++) bf[i] = *(const v8s*)&Bs[cur][(wn + rr + i * 16) * 32 + kc];
#pragma unroll
    for (int fm = 0; fm < 2; fm++)
#pragma unroll
      for (int fn = 0; fn < 2; fn++)
        mfma_bf16(acc[fm][fn], af[fm], bf[fn]);
    __syncthreads();
  }

  __builtin_amdgcn_sched_barrier(0);
  asm volatile("s_nop 7\ns_nop 7\ns_nop 7");
  __builtin_amdgcn_sched_barrier(0);

  const int r4 = (lane >> 4) << 2;
  const int cc = lane & 15;
#pragma unroll
  for (int fm = 0; fm < 2; fm++)
#pragma unroll
    for (int fn = 0; fn < 2; fn++)
#pragma unroll
      for (int i = 0; i < 4; i++) {
        int row = tiM + wm + fm * 16 + r4 + i;
        int col = tiN + wn + fn * 16 + cc;
        float v = acc[fm][fn][i];
        long long idx = (long long)row * ldc + col;
        float bb = bias ? bias[col] : 0.0f;
        ((float*)Cv)[idx] += v + bb;
      }
}

// ---------------------------------------------------------------------------
// ddq_qf_o: dd_q GEMM -> row-max -> exp (UNnormalized e to LDS, XOR-swizzled)
// -> fused {o_raw = e @ ctx^T, denom = e @ ksumb} via MFMA -> o = o_raw/denom
// -> head-scatter. qf never hits global.
// ---------------------------------------------------------------------------
__global__ void __launch_bounds__(384, 3)
ddq_qf_o(const u16* __restrict__ qr, const u16* __restrict__ proj,
         const float* __restrict__ diag, const u16* __restrict__ ksumb,
         const u16* __restrict__ ctxT, u16* __restrict__ obuf)
{
  extern __shared__ u16 dl[];
  __shared__ float redw[6][64];
  __shared__ float rowv[64];
  __shared__ float sdg[64];
  const int bh = blockIdx.z;
  const int tiM = blockIdx.x << 6;
  const int t = threadIdx.x;
  const int lane = t & 63;
  const int w = t >> 6;          // 0..5
  const u16* Ag = qr + (long long)bh * (N_SEQ * 64);
  const u16* Ap = Ag + (long long)(tiM + (t >> 2)) * 64 + ((t & 3) << 3);
  const int rr = lane & 15, kc = (lane >> 4) << 3;
  const int wn = w * 48;

  if (t < 64) sdg[t] = diag[(long long)bh * N_SEQ + tiM + t];

  v4f acc[4][3] = {};
  auto stage = [&](int buf, int k0) {
    if (t < 256) async16(Ap + k0, &dl[buf * 2048 + t * 8]);
#pragma unroll
    for (int j = 0; j < 3; j++) {
      int idx = j * 384 + t;
      async16(proj + (long long)(idx >> 2) * 64 + ((idx & 3) << 3) + k0,
              &dl[4096 + buf * 9216 + j * 3072 + t * 8]);
    }
  };

  stage(0, 0);
  __syncthreads();
  for (int kt = 0; kt < 2; ++kt) {
    if (kt == 0) stage(1, 32);
    v8s af[4], bf[3];
#pragma unroll
    for (int i = 0; i < 4; i++)
      af[i] = *(const v8s*)&dl[kt * 2048 + (rr + i * 16) * 32 + kc];
#pragma unroll
    for (int i = 0; i < 3; i++)
      bf[i] = *(const v8s*)&dl[4096 + kt * 9216 + (wn + i * 16 + rr) * 32 + kc];
#pragma unroll
    for (int fm = 0; fm < 4; fm++)
#pragma unroll
      for (int fn = 0; fn < 3; fn++)
        mfma_bf16(acc[fm][fn], af[fm], bf[fn]);
    __syncthreads();
  }

  __builtin_amdgcn_sched_barrier(0);
  asm volatile("s_nop 7\ns_nop 7\ns_nop 7");
  __builtin_amdgcn_sched_barrier(0);

  // early global loads: ctx tile + ksumb fragments (hide latency under softmax)
  v8s creg[6];
  const u16* cb = ctxT + (long long)bh * (64 * M_PAD);
#pragma unroll
  for (int j = 0; j < 6; j++) {
    int slot = j * 384 + t;       // row = slot/36, col8 = slot%36
    creg[j] = *(const v8s*)(cb + (slot / 36) * M_PAD + (slot % 36) * 8);
  }
  v8s kfrag[9];
  {
    const u16* kb = ksumb + bh * M_PAD;
    const v8s z = {};
#pragma unroll
    for (int kk = 0; kk < 9; kk++)
      kfrag[kk] = (rr == 0) ? *(const v8s*)(kb + kk * 32 + kc) : z;
  }

  const int r4 = (lane >> 4) << 2;
  const int cc = lane & 15;
  const float sc = 0.35355339f;

  // phase A: per-row max over valid cols (cross-wave for consistency)
#pragma unroll
  for (int fm = 0; fm < 4; fm++)
#pragma unroll
    for (int i = 0; i < 4; i++) {
      float m = -3e38f;
#pragma unroll
      for (int fn = 0; fn < 3; fn++) {
        int col = wn + fn * 16 + cc;
        float v = acc[fm][fn][i] * sc;
        if (col < M_FEAT) m = fmaxf(m, v);
      }
#pragma unroll
      for (int o = 1; o < 16; o <<= 1) m = fmaxf(m, __shfl_xor(m, o));
      if (cc == 0) redw[w][fm * 16 + r4 + i] = m;
    }
  __syncthreads();
  if (t < 64) {
    float g = redw[0][t];
#pragma unroll
    for (int ww = 1; ww < 6; ww++) g = fmaxf(g, redw[ww][t]);
    rowv[t] = g;
  }
  __syncthreads();

  // phase B+C: e = ratio*(exp(dd-diag-gm)+eps), store UNnormalized bf16 to
  // qfs with XOR-swizzled col.
#pragma unroll
  for (int fm = 0; fm < 4; fm++)
#pragma unroll
    for (int i = 0; i < 4; i++) {
      int row = fm * 16 + r4 + i;
      float gm = rowv[row];
      float dg = sdg[row];
      int swz = ((row >> 3) & 1) << 4;
#pragma unroll
      for (int fn = 0; fn < 3; fn++) {
        float e = 0.06131389f * (__expf(acc[fm][fn][i] * sc - dg - gm) + 1e-4f);
        int col = (wn + fn * 16 + cc) ^ swz;
        dl[row * 296 + col] = f2b(e);
      }
    }
  // ctx into cts[64][296] (base 18944)
#pragma unroll
  for (int j = 0; j < 6; j++) {
    int slot = j * 384 + t;
    *(v8s*)&dl[18944 + (slot / 36) * 296 + (slot % 36) * 8] = creg[j];
  }
  __syncthreads();

  // phase D: o_raw = e @ ctx; denom = e @ ksumb (extra MFMA column).
  if (w < 4) {
    v4f oacc[4] = {};
    v4f dacc = {};
    const int arow = w * 16 + rr;
    const int aswz = ((arow >> 3) & 1) << 4;
    for (int kk = 0; kk < 9; kk++) {
      v8s aq = *(const v8s*)&dl[arow * 296 + ((kk * 32 + kc) ^ aswz)];
      mfma_bf16(dacc, aq, kfrag[kk]);
#pragma unroll
      for (int et = 0; et < 4; et++) {
        v8s bc = *(const v8s*)&dl[18944 + (et * 16 + rr) * 296 + kk * 32 + kc];
        mfma_bf16(oacc[et], aq, bc);
      }
    }
    __builtin_amdgcn_sched_barrier(0);
    asm volatile("s_nop 7\ns_nop 7\ns_nop 7");
    __builtin_amdgcn_sched_barrier(0);
    const int b_ = bh >> 3, h_ = bh & 7;
    float dinv[4];
#pragma unroll
    for (int i = 0; i < 4; i++) {
      float dn = __shfl(dacc[i], lane & 48);   // col-0 lane of this row quad
      dinv[i] = 1.0f / dn;
    }
#pragma unroll
    for (int et = 0; et < 4; et++)
#pragma unroll
      for (int i = 0; i < 4; i++) {
        int n = tiM + w * 16 + r4 + i;
        obuf[((long long)(b_ * N_SEQ + n)) * 512 + h_ * 64 + et * 16 + cc] =
            f2b(oacc[et][i] * dinv[i]);
      }
  }
}

// ---------------------------------------------------------------------------
__global__ void ln_kernel(const float* __restrict__ x, const float* __restrict__ g,
                          const float* __restrict__ b, void* __restrict__ out)
{
  const int row = blockIdx.x * 4 + (threadIdx.x >> 6);
  const int lane = threadIdx.x & 63;
  const float* xr = x + (long long)row * D_MODEL + lane * 8;
  v4f v0 = *(const v4f*)xr;
  v4f v1 = *(const v4f*)(xr + 4);
  float s = v0[0] + v0[1] + v0[2] + v0[3] + v1[0] + v1[1] + v1[2] + v1[3];
  float sq = v0[0]*v0[0] + v0[1]*v0[1] + v0[2]*v0[2] + v0[3]*v0[3]
           + v1[0]*v1[0] + v1[1]*v1[1] + v1[2]*v1[2] + v1[3]*v1[3];
  s = wave_sum(s);
  sq = wave_sum(sq);
  float mu = s * (1.0f / D_MODEL);
  float var = sq * (1.0f / D_MODEL) - mu * mu;
  float rstd = rsqrtf(var + 1e-5f);
  v4f g0 = *(const v4f*)(g + lane * 8), g1 = *(const v4f*)(g + lane * 8 + 4);
  v4f bb0 = *(const v4f*)(b + lane * 8), bb1 = *(const v4f*)(b + lane * 8 + 4);
  float y[8];
#pragma unroll
  for (int j = 0; j < 4; j++) y[j] = (v0[j] - mu) * rstd * g0[j] + bb0[j];
#pragma unroll
  for (int j = 0; j < 4; j++) y[4 + j] = (v1[j] - mu) * rstd * g1[j] + bb1[j];
  u16* op = (u16*)out + (long long)row * D_MODEL + lane * 8;
  alignas(16) u16 tmp[8];
#pragma unroll
  for (int j = 0; j < 8; j++) tmp[j] = f2b(y[j]);
  *(v8s*)op = *(v8s*)tmp;
}

__global__ void posadd(const float* __restrict__ xin, float* __restrict__ x)
{
  long long i = (long long)blockIdx.x * 256 + threadIdx.x;
  int d = (int)(i & 511);
  int n = (int)((i >> 9) & 2047);
  int j = d & 255;
  float sarg = (float)n * expf(-0.035977892f * (float)j);
  float pe = (d < 256) ? sinf(sarg) : cosf(sarg);
  x[i] = xin[i] + pe;
}

__global__ void rotab(float* __restrict__ ts, float* __restrict__ tc)
{
  int i = blockIdx.x * 64 + threadIdx.x;  // 2048*32
  int n = i >> 5, j = i & 31;
  float sarg = (float)n * expf(-0.28782314f * (float)j);
  float s, c;
  sincosf(sarg, &s, &c);
  ts[i] = s;
  tc[i] = c;
}

// ---------------------------------------------------------------------------
// rotvt: fused rotary(q,k)+diag + v-transpose; also resets kmaxu (block 0).
// ---------------------------------------------------------------------------
__global__ void __launch_bounds__(256)
rotvt(const u16* __restrict__ qkv,
      const float* __restrict__ ts, const float* __restrict__ tc,
      u16* __restrict__ qr, u16* __restrict__ kr, u16* __restrict__ vT,
      float* __restrict__ dq, float* __restrict__ dk,
      unsigned int* __restrict__ kmaxu)
{
  __shared__ u16 st[64][72];
  const int bid = blockIdx.x;   // b*256 + h*32 + nt
  const int nt = bid & 31;
  const int h = (bid >> 5) & 7;
  const int b = bid >> 8;
  const int t = threadIdx.x;
  if (bid == 0 && t == 0) kmaxu[0] = 0u;
  const int r = t >> 3;
  const int cg = t & 7;
#pragma unroll
  for (int it = 0; it < 2; ++it) {
    const int nl = it * 32 + r;
    const int n = nt * 64 + nl;
    const long long src = ((long long)(b * N_SEQ + n)) * 1536 + h * 64 + cg * 8;
    v8s q8 = *(const v8s*)(qkv + src);
    v8s k8 = *(const v8s*)(qkv + src + 512);
    v8s v8 = *(const v8s*)(qkv + src + 1024);
    v4f sn = *(const v4f*)(ts + n * 32 + cg * 4);
    v4f cn = *(const v4f*)(tc + n * 32 + cg * 4);
    alignas(16) u16 qo[8], ko[8];
    float q2 = 0.0f, k2 = 0.0f;
#pragma unroll
    for (int j = 0; j < 4; j++) {
      float qe = b2f((u16)q8[2 * j]), qoe = b2f((u16)q8[2 * j + 1]);
      float ke = b2f((u16)k8[2 * j]), koe = b2f((u16)k8[2 * j + 1]);
      float c = cn[j], s = sn[j];
      float q0 = qe * c - qoe * s, q1 = qoe * c + qe * s;
      float k0 = ke * c - koe * s, k1 = koe * c + ke * s;
      qo[2 * j] = f2b(q0); qo[2 * j + 1] = f2b(q1);
      ko[2 * j] = f2b(k0); ko[2 * j + 1] = f2b(k1);
      q2 += q0 * q0 + q1 * q1;
      k2 += k0 * k0 + k1 * k1;
    }
    q2 += __shfl_xor(q2, 1); q2 += __shfl_xor(q2, 2); q2 += __shfl_xor(q2, 4);
    k2 += __shfl_xor(k2, 1); k2 += __shfl_xor(k2, 2); k2 += __shfl_xor(k2, 4);
    const long long rowidx = (long long)(b * 8 + h) * N_SEQ + n;
    if (cg == 0) {
      dq[rowidx] = q2 * 0.0625f;
      dk[rowidx] = k2 * 0.0625f;
    }
    *(v8s*)(qr + rowidx * 64 + cg * 8) = *(v8s*)qo;
    *(v8s*)(kr + rowidx * 64 + cg * 8) = *(v8s*)ko;
    *(v8s*)&st[nl][cg * 8] = v8;
  }
  __syncthreads();
  const int r2 = t >> 2, c2 = (t & 3) << 4;
  alignas(16) u16 tmp[16];
#pragma unroll
  for (int jj = 0; jj < 16; jj++) tmp[jj] = st[c2 + jj][r2];
  const long long dst = ((long long)((b * 8 + h) * 64 + r2)) * N_SEQ + nt * 64 + c2;
  *(v8s*)(vT + dst) = *(v8s*)&tmp[0];
  *(v8s*)(vT + dst + 8) = *(v8s*)&tmp[8];
}

__global__ void wtrans(const float* __restrict__ src, u16* __restrict__ dst,
                       int Ks, int Ns, long long sSrc, long long sDst)
{
  int l = blockIdx.z;
  src += (long long)l * sSrc;
  dst += (long long)l * sDst;
  int n0 = blockIdx.x << 6, k0 = blockIdx.y << 6;
  __shared__ float st[64][68];
  int t = threadIdx.x;
  int r = t >> 2, c = (t & 3) << 4;
  const float* sp = src + (long long)(k0 + r) * Ns + n0 + c;
#pragma unroll
  for (int jj = 0; jj < 16; jj += 4) *(v4f*)&st[r][c + jj] = *(const v4f*)(sp + jj);
  __syncthreads();
  alignas(16) u16 tmp[16];
#pragma unroll
  for (int jj = 0; jj < 16; jj++) tmp[jj] = f2b(st[c + jj][r]);
  u16* dp = dst + (long long)(n0 + r) * Ks + k0 + c;
  *(v8s*)(dp) = *(v8s*)&tmp[0];
  *(v8s*)(dp + 8) = *(v8s*)&tmp[8];
}

__global__ void projconv(const float* __restrict__ proj, u16* __restrict__ out)
{
  int i = blockIdx.x * 256 + threadIdx.x;  // 6*384*64
  int dh = i & 63;
  int m = (i >> 6) % M_ALLOC;
  int l = i / (M_ALLOC * 64);
  float v = (m < M_FEAT) ? proj[((long long)l * M_FEAT + m) * 64 + dh] : 0.0f;
  out[i] = f2b(v);
}

// reduce split-K ctx partials (8, stride M_PAD) + transpose -> ctxT bf16
__global__ void ctxred(const float* __restrict__ part, u16* __restrict__ ctxT)
{
  int bh = blockIdx.y;
  int m0 = blockIdx.x << 6;   // 5 tiles
  __shared__ float st[64][65];
  int t = threadIdx.x;
  int r = t >> 2, c = (t & 3) << 4;
  int m = m0 + r;
  v4f s[4] = {};
  if (m < M_PAD) {
    for (int ks = 0; ks < 8; ks++) {
      const float* p = part + (((long long)bh * 8 + ks) * M_PAD + m) * 64 + c;
#pragma unroll
      for (int j = 0; j < 4; j++) s[j] += *(const v4f*)(p + j * 4);
    }
  }
#pragma unroll
  for (int j = 0; j < 4; j++)
#pragma unroll
    for (int e = 0; e < 4; e++) st[r][c + j * 4 + e] = s[j][e];
  __syncthreads();
  int e = t >> 2, mc = (t & 3) << 4;
  if (m0 + mc < M_PAD) {
    alignas(16) u16 tmp[16];
#pragma unroll
    for (int j = 0; j < 16; j++) tmp[j] = f2b(st[mc + j][e]);
    u16* op = ctxT + ((long long)bh * 64 + e) * M_PAD + m0 + mc;
    *(v8s*)op = *(v8s*)&tmp[0];
    *(v8s*)(op + 8) = *(v8s*)&tmp[8];
  }
}

// ---------------------------------------------------------------------------
extern "C" void kernel_launch(void* const* d_in, const int* in_sizes, int n_in,
                              void* d_out, int out_size, void* d_ws, size_t ws_size,
                              hipStream_t stream)
{
  const float* x_in = (const float*)d_in[0];
  const float* Wq  = (const float*)d_in[1];
  const float* Wk  = (const float*)d_in[2];
  const float* Wv  = (const float*)d_in[3];
  const float* Wo  = (const float*)d_in[4];
  const float* Pr  = (const float*)d_in[5];
  const float* ln1g = (const float*)d_in[6];
  const float* ln1b = (const float*)d_in[7];
  const float* W1  = (const float*)d_in[8];
  const float* b1  = (const float*)d_in[9];
  const float* W2  = (const float*)d_in[10];
  const float* b2  = (const float*)d_in[11];
  const float* ln2g = (const float*)d_in[12];
  const float* ln2b = (const float*)d_in[13];
  const float* lnfg = (const float*)d_in[14];
  const float* lnfb = (const float*)d_in[15];

  hipFuncSetAttribute(reinterpret_cast<const void*>(&gemm4s<0, 1, 512>),
                      hipFuncAttributeMaxDynamicSharedMemorySize, 81920);
  hipFuncSetAttribute(reinterpret_cast<const void*>(&gemm4s<3, 1, 512>),
                      hipFuncAttributeMaxDynamicSharedMemorySize, 81920);
  hipFuncSetAttribute(reinterpret_cast<const void*>(&gemm4s<5, 2, 2048>),
                      hipFuncAttributeMaxDynamicSharedMemorySize, 81920);
  hipFuncSetAttribute(reinterpret_cast<const void*>(&ddq_qf_o),
                      hipFuncAttributeMaxDynamicSharedMemorySize, 75776);

  char* ws = (char*)d_ws;
  size_t off = 0;
  auto alloc = [&](size_t bytes) -> void* {
    void* p = ws + off;
    off = (off + bytes + 255) & ~(size_t)255;
    return p;
  };

  float* x      = (float*)alloc((size_t)ROWS * D_MODEL * 4);
  float* tsin   = (float*)alloc((size_t)N_SEQ * 32 * 4);
  float* tcos   = (float*)alloc((size_t)N_SEQ * 32 * 4);
  u16*   wqkvT  = (u16*)alloc((size_t)N_LAYER * 1536 * 512 * 2);
  u16*   woT    = (u16*)alloc((size_t)N_LAYER * 512 * 512 * 2);
  u16*   w1T    = (u16*)alloc((size_t)N_LAYER * 2048 * 512 * 2);
  u16*   w2T    = (u16*)alloc((size_t)N_LAYER * 512 * 2048 * 2);
  u16*   projT  = (u16*)alloc((size_t)N_LAYER * M_ALLOC * 64 * 2);
  u16*   hbuf   = (u16*)alloc((size_t)ROWS * D_MODEL * 2);
  u16*   obuf   = (u16*)alloc((size_t)ROWS * D_MODEL * 2);
  float* big    = (float*)alloc((size_t)32 * N_SEQ * M_PAD * 4);   // qkv_pre bf16 / ff bf16
  u16*   qrbuf  = (u16*)alloc((size_t)BHN * 64 * 2);
  u16*   krbuf  = (u16*)alloc((size_t)BHN * 64 * 2);
  u16*   vTbuf  = (u16*)alloc((size_t)BHN * 64 * 2);
  float* diagq  = (float*)alloc((size_t)BHN * 4);
  float* diagk  = (float*)alloc((size_t)BHN * 4);
  unsigned int* kmaxu = (unsigned int*)alloc(256);
  u16*   kfT    = (u16*)alloc((size_t)32 * M_ALLOC * N_SEQ * 2);
  float* part   = (float*)alloc((size_t)32 * 8 * M_PAD * 64 * 4);
  float* kspart = (float*)alloc((size_t)32 * M_PAD * 32 * 4);
  u16*   ctxT   = (u16*)alloc((size_t)32 * 64 * M_PAD * 2);
  float* ksum   = (float*)alloc((size_t)32 * M_PAD * 4);
  u16*   ksumb  = (u16*)alloc((size_t)32 * M_PAD * 2);
  (void)alloc(1 << 20);  // guard region for benign OOB tile reads
  (void)ws_size; (void)in_sizes; (void)n_in; (void)out_size;
  // FF2 split-K partials (2 x 16 MB) alias kfT: kfT is dead by FF2 time each
  // layer; both regions are rewritten next layer.
  float* ff2part = (float*)kfT;

  // ---- setup ----
  posadd<<<16384, 256, 0, stream>>>(x_in, x);
  rotab<<<1024, 64, 0, stream>>>(tsin, tcos);
  wtrans<<<dim3(8, 8, 6), 256, 0, stream>>>(Wq, wqkvT, 512, 512, 512LL * 512, 1536LL * 512);
  wtrans<<<dim3(8, 8, 6), 256, 0, stream>>>(Wk, wqkvT + 512LL * 512, 512, 512, 512LL * 512, 1536LL * 512);
  wtrans<<<dim3(8, 8, 6), 256, 0, stream>>>(Wv, wqkvT + 1024LL * 512, 512, 512, 512LL * 512, 1536LL * 512);
  wtrans<<<dim3(8, 8, 6), 256, 0, stream>>>(Wo, woT, 512, 512, 512LL * 512, 512LL * 512);
  wtrans<<<dim3(32, 8, 6), 256, 0, stream>>>(W1, w1T, 512, 2048, 512LL * 2048, 2048LL * 512);
  wtrans<<<dim3(8, 32, 6), 256, 0, stream>>>(W2, w2T, 2048, 512, 2048LL * 512, 512LL * 2048);
  projconv<<<(N_LAYER * M_ALLOC * 64) / 256, 256, 0, stream>>>(Pr, projT);

  // LN1 for layer 0 (later layers get it fused into ff2red_ln)
  ln_kernel<<<ROWS / 4, 256, 0, stream>>>(x, ln1g, ln1b, hbuf);

  for (int l = 0; l < N_LAYER; l++) {
    const u16* wq = wqkvT + (long long)l * 1536 * 512;
    const u16* wo = woT + (long long)l * 512 * 512;
    const u16* w1 = w1T + (long long)l * 2048 * 512;
    const u16* w2 = w2T + (long long)l * 512 * 2048;
    const u16* pj = projT + (long long)l * M_ALLOC * 64;

    // qkv_pre = h @ Wqkv^T  (8192 x 1536, K=512)
    gemm4s<0, 1, 512><<<dim3(64, 6), 512, 81920, stream>>>(hbuf, wq, big, nullptr, 1536);
    // fused rotary + diag + v-transpose (+ kmax reset)
    rotvt<<<1024, 256, 0, stream>>>((u16*)big, tsin, tcos, qrbuf, krbuf, vTbuf,
                                    diagq, diagk, kmaxu);
    // pass A: global k-max only (no dd store)
    gemm2<7, 128, 1><<<dim3(512, 3, 1), 256, 0, stream>>>(krbuf, pj, nullptr, nullptr,
        64, M_PAD, 0, 0, 0, 0.35355339f, M_PAD, BHN, kmaxu);
    // pass B: recompute + fused exp -> kfT + ksum partials
    kf_gemm<<<dim3(32, 1, 32), 384, 0, stream>>>(krbuf, pj, diagk, kmaxu, kfT, kspart);
    ksumred<<<(32 * M_PAD + 255) / 256, 256, 0, stream>>>(kspart, ksum, ksumb);
    // ctx = kf^T @ v  split-K=8 (partials stride M_PAD)
    gemm2<5, 64, 8><<<dim3(3, 1, 256), 256, 0, stream>>>(kfT, vTbuf, part, nullptr,
        2048, 64, (long long)M_ALLOC * N_SEQ, 64LL * N_SEQ, 0, 1.0f, 64, M_PAD, nullptr);
    ctxred<<<dim3(5, 32), 256, 0, stream>>>(part, ctxT);
    // fused dd_q -> e (LDS) -> {o_raw, denom} MFMA -> o scatter
    ddq_qf_o<<<dim3(32, 1, 32), 384, 75776, stream>>>(qrbuf, pj, diagq, ksumb, ctxT, obuf);
    // x += o @ Wo^T
    gemm_small<2, 512><<<dim3(128, 8, 1), 256, 0, stream>>>(obuf, wo, x, nullptr,
        512, 0, 0);
    // LN2 -> h
    ln_kernel<<<ROWS / 4, 256, 0, stream>>>(x, ln2g + l * 512, ln2b + l * 512, hbuf);
    // ff = gelu(h @ W1^T + b1)
    gemm4s<3, 1, 512><<<dim3(64, 8), 512, 81920, stream>>>(hbuf, w1, big,
        b1 + (long long)l * 2048, 2048);
    // ff2 partials = ff @ W2^T  [split-K=2]
    gemm4s<5, 2, 2048><<<dim3(64, 2, 2), 512, 81920, stream>>>((u16*)big, w2, ff2part,
        nullptr, 512);
    // x += sum(partials) + b2; fused LN (next layer's LN1, or final LN -> d_out)
    if (l < N_LAYER - 1) {
      ff2red_ln<false, 2><<<2048, 256, 0, stream>>>(ff2part, b2 + (long long)l * 512, x,
          ln1g + (long long)(l + 1) * 512, ln1b + (long long)(l + 1) * 512, hbuf);
    } else {
      ff2red_ln<true, 2><<<2048, 256, 0, stream>>>(ff2part, b2 + (long long)l * 512, x,
          lnfg, lnfb, d_out);
    }
  }
}

// Round 21
// 1302.022 us; speedup vs baseline: 1.0148x; 1.0148x over previous
//
#include <hip/hip_runtime.h>
#include <hip/hip_bf16.h>
#include <cstdint>

typedef float v4f __attribute__((ext_vector_type(4)));
typedef short v8s __attribute__((ext_vector_type(8)));
typedef unsigned short u16;

#define N_SEQ 2048
#define D_MODEL 512
#define N_LAYER 6
#define N_HEAD 8
#define D_HEAD 64
#define M_FEAT 266
#define M_PAD 288
#define M_ALLOC 384
#define FF_DIM 2048
#define BATCH 4
#define ROWS 8192
#define BHN 65536   // B*H*N

__device__ __forceinline__ float b2f(u16 u) {
  return __uint_as_float(((uint32_t)u) << 16);
}
__device__ __forceinline__ u16 f2b(float f) {
  union { __hip_bfloat16 h; u16 u; } c;
  c.h = __float2bfloat16(f);
  return c.u;
}
__device__ __forceinline__ float wave_sum(float v) {
#pragma unroll
  for (int o = 1; o < 64; o <<= 1) v += __shfl_xor(v, o);
  return v;
}
__device__ __forceinline__ float wave_max(float v) {
#pragma unroll
  for (int o = 1; o < 64; o <<= 1) v = fmaxf(v, __shfl_xor(v, o));
  return v;
}

// exact-erf gelu via Abramowitz-Stegun 7.1.26 (|erf err| <= 1.5e-7)
__device__ __forceinline__ float gelu_f(float x) {
  float ax = fabsf(x) * 0.70710678118f;
  float tt = __builtin_amdgcn_rcpf(fmaf(0.3275911f, ax, 1.0f));
  float poly = tt * fmaf(tt, fmaf(tt, fmaf(tt, fmaf(tt, 1.061405429f, -1.453152027f),
                                           1.421413741f), -0.284496736f), 0.254829592f);
  float er = 1.0f - poly * __expf(-ax * ax);
  er = copysignf(er, x);
  return 0.5f * x * (1.0f + er);
}

__device__ __forceinline__ void mfma_bf16(v4f& d, v8s a, v8s b) {
  asm volatile("v_mfma_f32_16x16x32_bf16 %0, %1, %2, %0" : "+v"(d) : "v"(a), "v"(b));
}

// async global->LDS, 16B per lane. LDS dest must be wave-linear (base + lane*16).
__device__ __forceinline__ void async16(const u16* g, u16* l) {
  __builtin_amdgcn_global_load_lds(
      (const __attribute__((address_space(1))) uint32_t*)g,
      (__attribute__((address_space(3))) uint32_t*)l, 16, 0, 0);
}

// ---------------------------------------------------------------------------
// gemm4s: 128x256 tile, BK=32, 512 threads (8 waves 2Mx4N, 64x64 each).
// Asymmetric dual ring: A 4 slots, B 3 slots; counted vmcnt(4). 80KB LDS.
// KTOT is compile-time -> K-loop FULLY UNROLLED: slot indices, staging
// branches and vmcnt selection all constant-fold.
// EPI: 0 = bf16 out; 3 = bf16 gelu(acc + bias); 5 = f32 split partial.
// ---------------------------------------------------------------------------
template <int EPI, int KSPLIT, int KTOT>
__global__ void __launch_bounds__(512, 4)
gemm4s(const u16* __restrict__ A, const u16* __restrict__ B,
       void* __restrict__ Cv, const float* __restrict__ bias,
       int ldc)
{
  extern __shared__ u16 lds[];
  const int t = threadIdx.x;
  const int lane = t & 63;
  const int w = t >> 6;
  const int wm = w >> 2;
  const int wn = w & 3;
  const int tiM = blockIdx.x << 7, tiN = blockIdx.y << 8;
  const int ks = (KSPLIT > 1) ? blockIdx.z : 0;
  constexpr int kchunk = KTOT / KSPLIT;
  constexpr int NT = kchunk >> 5;
  static_assert(NT >= 4, "pipeline needs >= 4 K-tiles");

  const int rr = lane & 15;
  const int kq = (lane >> 4) << 3;
  const int sw = ((rr >> 1) & 3) << 3;
  const int cr = kq ^ sw;

  const int srow = t >> 2;
  const int scol = (((t & 3) ^ ((srow >> 1) & 3)) << 3);
  const u16* Abase = A + (long long)(tiM + srow) * KTOT + scol + (long long)ks * kchunk;
  const u16* Bbase = B + (long long)(tiN + srow) * KTOT + scol + (long long)ks * kchunk;
  constexpr long long r128 = 128LL * KTOT;

  v4f acc[4][4] = {};

  auto stageA = [&](int s, int kt) {
    async16(Abase + (long long)kt * 32, &lds[s * 4096 + t * 8]);
  };
  auto stageB = [&](int s, int kt) {
    u16* d = &lds[16384 + s * 8192 + t * 8];
    async16(Bbase + (long long)kt * 32, d);
    async16(Bbase + (long long)kt * 32 + r128, d + 4096);
  };

  stageB(0, 0);
  stageA(0, 0);
  stageB(1, 1);
  stageA(1, 1);
  stageA(2, 2);
  asm volatile("s_waitcnt vmcnt(4)" ::: "memory");
  __builtin_amdgcn_s_barrier();

#pragma unroll
  for (int kt = 0; kt < NT; ++kt) {
    const int ab = (kt & 3) * 4096;          // compile-time per unrolled iter
    const int bb = 16384 + (kt % 3) * 8192;  // compile-time per unrolled iter
    if (kt + 2 < NT) stageB((kt + 2) % 3, kt + 2);
    if (kt + 3 < NT) stageA((kt + 3) & 3, kt + 3);
    v8s af[4], bf[4];
#pragma unroll
    for (int i = 0; i < 4; i++) {
      af[i] = *(const v8s*)&lds[ab + (wm * 64 + i * 16 + rr) * 32 + cr];
      bf[i] = *(const v8s*)&lds[bb + (wn * 64 + i * 16 + rr) * 32 + cr];
    }
    __builtin_amdgcn_s_setprio(1);
#pragma unroll
    for (int m = 0; m < 4; m++)
#pragma unroll
      for (int n = 0; n < 4; n++) mfma_bf16(acc[m][n], af[m], bf[n]);
    __builtin_amdgcn_s_setprio(0);
    if (kt + 1 < NT) {
      if (kt + 3 < NT)      asm volatile("s_waitcnt vmcnt(4)" ::: "memory");
      else if (kt + 2 < NT) asm volatile("s_waitcnt vmcnt(3)" ::: "memory");
      else                  asm volatile("s_waitcnt vmcnt(0)" ::: "memory");
      __builtin_amdgcn_s_barrier();
    }
  }

  __builtin_amdgcn_sched_barrier(0);
  asm volatile("s_nop 7\ns_nop 7\ns_nop 7");
  __builtin_amdgcn_sched_barrier(0);

  const int r4 = (lane >> 4) << 2;
  const int cc = lane & 15;
#pragma unroll
  for (int mf = 0; mf < 4; mf++)
#pragma unroll
    for (int nf = 0; nf < 4; nf++)
#pragma unroll
      for (int i = 0; i < 4; i++) {
        int row = tiM + wm * 64 + mf * 16 + r4 + i;
        int col = tiN + wn * 64 + nf * 16 + cc;
        float v = acc[mf][nf][i];
        if (EPI == 0) {
          ((u16*)Cv)[(long long)row * ldc + col] = f2b(v);
        } else if (EPI == 3) {
          ((u16*)Cv)[(long long)row * ldc + col] = f2b(gelu_f(v + bias[col]));
        } else {  // EPI == 5: f32 split partial
          ((float*)Cv)[((long long)ks * ROWS + row) * ldc + col] = v;
        }
      }
}

// ---------------------------------------------------------------------------
// ff2red_ln: x_new = x + sum of NSPLIT FF2 partials + b2; then LN(x_new).
// ---------------------------------------------------------------------------
template <bool LAST, int NSPLIT>
__global__ void ff2red_ln(const float* __restrict__ part, const float* __restrict__ bias,
                          float* __restrict__ x, const float* __restrict__ g,
                          const float* __restrict__ bvec, void* __restrict__ out)
{
  const int row = blockIdx.x * 4 + (threadIdx.x >> 6);
  const int lane = threadIdx.x & 63;
  const long long base = (long long)row * D_MODEL + lane * 8;
  v4f s0 = {}, s1 = {};
#pragma unroll
  for (int ks = 0; ks < NSPLIT; ks++) {
    const float* p = part + (long long)ks * (ROWS * 512LL) + base;
    s0 += *(const v4f*)p;
    s1 += *(const v4f*)(p + 4);
  }
  v4f b0 = *(const v4f*)(bias + lane * 8);
  v4f b1 = *(const v4f*)(bias + lane * 8 + 4);
  v4f x0 = *(const v4f*)(x + base) + s0 + b0;
  v4f x1 = *(const v4f*)(x + base + 4) + s1 + b1;
  if (!LAST) {
    *(v4f*)(x + base) = x0;
    *(v4f*)(x + base + 4) = x1;
  }
  float s = x0[0] + x0[1] + x0[2] + x0[3] + x1[0] + x1[1] + x1[2] + x1[3];
  float sq = x0[0]*x0[0] + x0[1]*x0[1] + x0[2]*x0[2] + x0[3]*x0[3]
           + x1[0]*x1[0] + x1[1]*x1[1] + x1[2]*x1[2] + x1[3]*x1[3];
  s = wave_sum(s);
  sq = wave_sum(sq);
  float mu = s * (1.0f / D_MODEL);
  float var = sq * (1.0f / D_MODEL) - mu * mu;
  float rstd = rsqrtf(var + 1e-5f);
  v4f g0 = *(const v4f*)(g + lane * 8), g1 = *(const v4f*)(g + lane * 8 + 4);
  v4f bb0 = *(const v4f*)(bvec + lane * 8), bb1 = *(const v4f*)(bvec + lane * 8 + 4);
  float y[8];
#pragma unroll
  for (int j = 0; j < 4; j++) y[j] = (x0[j] - mu) * rstd * g0[j] + bb0[j];
#pragma unroll
  for (int j = 0; j < 4; j++) y[4 + j] = (x1[j] - mu) * rstd * g1[j] + bb1[j];
  if (LAST) {
    float* op = (float*)out + base;
    v4f o0 = {y[0], y[1], y[2], y[3]}, o1 = {y[4], y[5], y[6], y[7]};
    *(v4f*)op = o0;
    *(v4f*)(op + 4) = o1;
  } else {
    u16* op = (u16*)out + base;
    alignas(16) u16 tmp[8];
#pragma unroll
    for (int j = 0; j < 8; j++) tmp[j] = f2b(y[j]);
    *(v8s*)op = *(v8s*)tmp;
  }
}

// ---------------------------------------------------------------------------
// gemm2: BM=128, BN in {64,128}.
// EPI: 5 = f32 split-K partial (stride M_PAD); 7 = max-only + fused atomicMax
// ---------------------------------------------------------------------------
template <int EPI, int BN, int KSPLIT>
__global__ void __launch_bounds__(256, 4)
gemm2(const u16* __restrict__ A, const u16* __restrict__ B,
      void* __restrict__ Cv, const float* __restrict__ bias,
      int K, int ldc, long long sA, long long sB, long long sC,
      float scale, int Ncap, int Mcap, unsigned int* __restrict__ gmax)
{
  __shared__ u16 As[2][128 * 32];
  __shared__ u16 Bs[2][BN * 32];
  __shared__ float smax[4];
  const int zz = blockIdx.z;
  const int z = (KSPLIT > 1) ? zz / KSPLIT : zz;
  const int ks = (KSPLIT > 1) ? zz % KSPLIT : 0;
  const int kchunk = K / KSPLIT;
  const u16* Ag = A + (long long)z * sA + ks * kchunk;
  const u16* Bg = B + (long long)z * sB + ks * kchunk;
  const int t = threadIdx.x;
  const int lane = t & 63;
  const int w = t >> 6;
  constexpr int NF = BN / 32;
  const int wm = (w >> 1) << 6;
  const int wn = (w & 1) * (BN / 2);
  const int tiM = blockIdx.x << 7, tiN = blockIdx.y * BN;

  const int srow = t >> 2;
  const int scol = (t & 3) << 3;
  const u16* Ap = Ag + (long long)(tiM + srow) * K + scol;
  const u16* Bp = Bg + (long long)(tiN + srow) * K + scol;
  const long long rstride = 64LL * K;

  const int rr = lane & 15;
  const int kc = (lane >> 4) << 3;

  v4f acc[4][NF] = {};

  const int nk = kchunk >> 5;
  auto stage = [&](int buf, int k0) {
    async16(Ap + k0, &As[buf][t * 8]);
    async16(Ap + k0 + rstride, &As[buf][t * 8 + 2048]);
    async16(Bp + k0, &Bs[buf][t * 8]);
    if (BN == 128) async16(Bp + k0 + rstride, &Bs[buf][t * 8 + 2048]);
  };

  stage(0, 0);
  __syncthreads();
  int cur = 0;
  for (int kt = 0; kt < nk; ++kt) {
    if (kt + 1 < nk) stage(cur ^ 1, (kt + 1) << 5);
    v8s af[4], bf[NF];
#pragma unroll
    for (int i = 0; i < 4; i++) af[i] = *(const v8s*)&As[cur][(wm + rr + i * 16) * 32 + kc];
#pragma unroll
    for (int i = 0; i < NF; i++) bf[i] = *(const v8s*)&Bs[cur][(wn + rr + i * 16) * 32 + kc];
#pragma unroll
    for (int fm = 0; fm < 4; fm++)
#pragma unroll
      for (int fn = 0; fn < NF; fn++)
        mfma_bf16(acc[fm][fn], af[fm], bf[fn]);
    __syncthreads();
    cur ^= 1;
  }

  __builtin_amdgcn_sched_barrier(0);
  asm volatile("s_nop 7\ns_nop 7\ns_nop 7");
  __builtin_amdgcn_sched_barrier(0);

  const int r4 = (lane >> 4) << 2;
  const int cc = lane & 15;
  float lmax = -3e38f;
#pragma unroll
  for (int fm = 0; fm < 4; fm++)
#pragma unroll
    for (int fn = 0; fn < NF; fn++)
#pragma unroll
      for (int i = 0; i < 4; i++) {
        int row = tiM + wm + fm * 16 + r4 + i;
        int col = tiN + wn + fn * 16 + cc;
        float v = acc[fm][fn][i];
        if (EPI == 5) {
          if (row < Mcap && col < Ncap)
            ((float*)Cv)[((long long)zz * M_PAD + row) * 64 + col] = v;
        } else if (EPI == 7) {
          if (col < M_FEAT) lmax = fmaxf(lmax, v * scale);
        }
      }

  if (EPI == 7) {
    lmax = wave_max(lmax);
    if (lane == 0) smax[w] = lmax;
    __syncthreads();
    if (t == 0) {
      float m = fmaxf(fmaxf(smax[0], smax[1]), fmaxf(smax[2], smax[3]));
      unsigned int u = __float_as_uint(m);
      unsigned int key = (u & 0x80000000u) ? ~u : (u | 0x80000000u);
      atomicMax(gmax, key);
    }
  }
}

// ---------------------------------------------------------------------------
// kf_gemm: transposed K-feature GEMM + fused exp epilogue (dd never stored).
// ---------------------------------------------------------------------------
__global__ void __launch_bounds__(384, 3)
kf_gemm(const u16* __restrict__ kr, const u16* __restrict__ proj,
        const float* __restrict__ diagk, const unsigned int* __restrict__ kmax,
        u16* __restrict__ kfT, float* __restrict__ part)
{
  __shared__ u16 As[2][288 * 32];   // proj rows m
  __shared__ u16 Bs[2][64 * 32];    // k_rot rows n
  __shared__ float sdg[64];
  const int ntile = blockIdx.x;     // 0..31
  const int bh = blockIdx.z;        // 0..31
  const int n0 = ntile << 6;
  const int t = threadIdx.x;
  const int lane = t & 63;
  const int w = t >> 6;             // 0..5
  const u16* Bg = kr + (long long)bh * (N_SEQ * 64) + (long long)n0 * 64;
  const int rr = lane & 15, kc = (lane >> 4) << 3;

  if (t < 64) sdg[t] = diagk[(long long)bh * N_SEQ + n0 + t];
  unsigned int kk = kmax[0];
  const float km = (kk & 0x80000000u) ? __uint_as_float(kk ^ 0x80000000u)
                                      : __uint_as_float(~kk);

  v4f acc[3][4] = {};
  auto stage = [&](int buf, int k0) {
#pragma unroll
    for (int j = 0; j < 3; j++) {
      int idx = j * 384 + t;        // proj rows 0..287
      async16(proj + (long long)(idx >> 2) * 64 + ((idx & 3) << 3) + k0,
              &As[buf][j * 3072 + t * 8]);
    }
    if (t < 256) async16(Bg + (long long)(t >> 2) * 64 + ((t & 3) << 3) + k0,
                         &Bs[buf][t * 8]);
  };

  stage(0, 0);
  __syncthreads();
  for (int kt = 0; kt < 2; ++kt) {
    if (kt == 0) stage(1, 32);
    v8s af[3], bf[4];
#pragma unroll
    for (int i = 0; i < 3; i++) af[i] = *(const v8s*)&As[kt][(w * 48 + i * 16 + rr) * 32 + kc];
#pragma unroll
    for (int i = 0; i < 4; i++) bf[i] = *(const v8s*)&Bs[kt][(i * 16 + rr) * 32 + kc];
#pragma unroll
    for (int fm = 0; fm < 3; fm++)
#pragma unroll
      for (int fn = 0; fn < 4; fn++)
        mfma_bf16(acc[fm][fn], af[fm], bf[fn]);
    __syncthreads();
  }

  __builtin_amdgcn_sched_barrier(0);
  asm volatile("s_nop 7\ns_nop 7\ns_nop 7");
  __builtin_amdgcn_sched_barrier(0);

  const int r4 = (lane >> 4) << 2;
  const int cc = lane & 15;
  const float sc = 0.35355339f;

#pragma unroll
  for (int fm = 0; fm < 3; fm++)
#pragma unroll
    for (int i = 0; i < 4; i++) {
      int m = w * 48 + fm * 16 + r4 + i;
      float s = 0.0f;
#pragma unroll
      for (int fn = 0; fn < 4; fn++) {
        float dd = acc[fm][fn][i] * sc;
        float kf = (m < M_FEAT)
            ? 0.06131389f * (__expf(dd - sdg[fn * 16 + cc] - km) + 1e-4f) : 0.0f;
        acc[fm][fn][i] = kf;
        s += kf;
        kfT[((long long)bh * M_ALLOC + m) * N_SEQ + n0 + fn * 16 + cc] = f2b(kf);
      }
#pragma unroll
      for (int o = 1; o < 16; o <<= 1) s += __shfl_xor(s, o);
      if (cc == 0) part[((long long)bh * M_PAD + m) * 32 + ntile] = s;
    }
}

// ksum reduce: f32 sum + bf16 copy (for the MFMA denominator in ddq_qf_o)
__global__ void ksumred(const float* __restrict__ part, float* __restrict__ ksum,
                        u16* __restrict__ ksumb)
{
  int i = blockIdx.x * 256 + threadIdx.x;  // 32*288
  if (i >= 32 * M_PAD) return;
  const float* p = part + (long long)i * 32;
  float s = 0.0f;
#pragma unroll
  for (int j = 0; j < 32; j += 4) {
    v4f v = *(const v4f*)(p + j);
    s += v[0] + v[1] + v[2] + v[3];
  }
  ksum[i] = s;
  ksumb[i] = f2b(s);
}

// ---------------------------------------------------------------------------
// gemm_small: BM=64, BN=64, BK=32, compile-time K (unrolled loop).
// EPI 2 = f32 residual += acc + bias.
// ---------------------------------------------------------------------------
template <int EPI, int K>
__global__ void __launch_bounds__(256, 6)
gemm_small(const u16* __restrict__ A, const u16* __restrict__ B,
           void* __restrict__ Cv, const float* __restrict__ bias,
           int ldc, long long sA, long long sB)
{
  __shared__ u16 As[2][64 * 32];
  __shared__ u16 Bs[2][64 * 32];
  const int z = blockIdx.z;
  const u16* Ag = A + (long long)z * sA;
  const u16* Bg = B + (long long)z * sB;
  const int t = threadIdx.x;
  const int lane = t & 63;
  const int w = t >> 6;
  const int wm = (w >> 1) << 5;
  const int wn = (w & 1) << 5;
  const int tiM = blockIdx.x << 6, tiN = blockIdx.y << 6;

  const int srow = t >> 2;
  const int scol = (t & 3) << 3;
  const u16* Ap = Ag + (long long)(tiM + srow) * K + scol;
  const u16* Bp = Bg + (long long)(tiN + srow) * K + scol;

  const int rr = lane & 15;
  const int kc = (lane >> 4) << 3;

  v4f acc[2][2] = {};

  constexpr int nk = K >> 5;
  auto stage = [&](int buf, int k0) {
    async16(Ap + k0, &As[buf][t * 8]);
    async16(Bp + k0, &Bs[buf][t * 8]);
  };

  stage(0, 0);
  __syncthreads();
#pragma unroll
  for (int kt = 0; kt < nk; ++kt) {
    const int cur = kt & 1;
    if (kt + 1 < nk) stage(cur ^ 1, (kt + 1) << 5);
    v8s af[2], bf[2];
#pragma unroll
    for (int i = 0; i < 2; i++) af[i] = *(const v8s*)&As[cur][(wm + rr + i * 16) * 32 + kc];
#pragma unroll
    for (int i = 0; i < 2; i++) bf[i] = *(const v8s*)&Bs[cur][(wn + rr + i * 16) * 32 + kc];
#pragma unroll
    for (int fm = 0; fm < 2; fm++)
#pragma unroll
      for (int fn = 0; fn < 2; fn++)
        mfma_bf16(acc[fm][fn], af[fm], bf[fn]);
    __syncthreads();
  }

  __builtin_amdgcn_sched_barrier(0);
  asm volatile("s_nop 7\ns_nop 7\ns_nop 7");
  __builtin_amdgcn_sched_barrier(0);

  const int r4 = (lane >> 4) << 2;
  const int cc = lane & 15;
#pragma unroll
  for (int fm = 0; fm < 2; fm++)
#pragma unroll
    for (int fn = 0; fn < 2; fn++)
#pragma unroll
      for (int i = 0; i < 4; i++) {
        int row = tiM + wm + fm * 16 + r4 + i;
        int col = tiN + wn + fn * 16 + cc;
        float v = acc[fm][fn][i];
        long long idx = (long long)row * ldc + col;
        float bb = bias ? bias[col] : 0.0f;
        ((float*)Cv)[idx] += v + bb;
      }
}

// ---------------------------------------------------------------------------
// ddq_qf_o: dd_q GEMM -> row-max -> exp (UNnormalized e to LDS, XOR-swizzled)
// -> fused {o_raw = e @ ctx^T, denom = e @ ksumb} via MFMA -> o = o_raw/denom
// -> head-scatter. qf never hits global.
// ---------------------------------------------------------------------------
__global__ void __launch_bounds__(384, 3)
ddq_qf_o(const u16* __restrict__ qr, const u16* __restrict__ proj,
         const float* __restrict__ diag, const u16* __restrict__ ksumb,
         const u16* __restrict__ ctxT, u16* __restrict__ obuf)
{
  extern __shared__ u16 dl[];
  __shared__ float redw[6][64];
  __shared__ float rowv[64];
  __shared__ float sdg[64];
  const int bh = blockIdx.z;
  const int tiM = blockIdx.x << 6;
  const int t = threadIdx.x;
  const int lane = t & 63;
  const int w = t >> 6;          // 0..5
  const u16* Ag = qr + (long long)bh * (N_SEQ * 64);
  const u16* Ap = Ag + (long long)(tiM + (t >> 2)) * 64 + ((t & 3) << 3);
  const int rr = lane & 15, kc = (lane >> 4) << 3;
  const int wn = w * 48;

  if (t < 64) sdg[t] = diag[(long long)bh * N_SEQ + tiM + t];

  v4f acc[4][3] = {};
  auto stage = [&](int buf, int k0) {
    if (t < 256) async16(Ap + k0, &dl[buf * 2048 + t * 8]);
#pragma unroll
    for (int j = 0; j < 3; j++) {
      int idx = j * 384 + t;
      async16(proj + (long long)(idx >> 2) * 64 + ((idx & 3) << 3) + k0,
              &dl[4096 + buf * 9216 + j * 3072 + t * 8]);
    }
  };

  stage(0, 0);
  __syncthreads();
  for (int kt = 0; kt < 2; ++kt) {
    if (kt == 0) stage(1, 32);
    v8s af[4], bf[3];
#pragma unroll
    for (int i = 0; i < 4; i++)
      af[i] = *(const v8s*)&dl[kt * 2048 + (rr + i * 16) * 32 + kc];
#pragma unroll
    for (int i = 0; i < 3; i++)
      bf[i] = *(const v8s*)&dl[4096 + kt * 9216 + (wn + i * 16 + rr) * 32 + kc];
#pragma unroll
    for (int fm = 0; fm < 4; fm++)
#pragma unroll
      for (int fn = 0; fn < 3; fn++)
        mfma_bf16(acc[fm][fn], af[fm], bf[fn]);
    __syncthreads();
  }

  __builtin_amdgcn_sched_barrier(0);
  asm volatile("s_nop 7\ns_nop 7\ns_nop 7");
  __builtin_amdgcn_sched_barrier(0);

  // early global loads: ctx tile + ksumb fragments (hide latency under softmax)
  v8s creg[6];
  const u16* cb = ctxT + (long long)bh * (64 * M_PAD);
#pragma unroll
  for (int j = 0; j < 6; j++) {
    int slot = j * 384 + t;       // row = slot/36, col8 = slot%36
    creg[j] = *(const v8s*)(cb + (slot / 36) * M_PAD + (slot % 36) * 8);
  }
  v8s kfrag[9];
  {
    const u16* kb = ksumb + bh * M_PAD;
    const v8s z = {};
#pragma unroll
    for (int kk = 0; kk < 9; kk++)
      kfrag[kk] = (rr == 0) ? *(const v8s*)(kb + kk * 32 + kc) : z;
  }

  const int r4 = (lane >> 4) << 2;
  const int cc = lane & 15;
  const float sc = 0.35355339f;

  // phase A: per-row max over valid cols (cross-wave for consistency)
#pragma unroll
  for (int fm = 0; fm < 4; fm++)
#pragma unroll
    for (int i = 0; i < 4; i++) {
      float m = -3e38f;
#pragma unroll
      for (int fn = 0; fn < 3; fn++) {
        int col = wn + fn * 16 + cc;
        float v = acc[fm][fn][i] * sc;
        if (col < M_FEAT) m = fmaxf(m, v);
      }
#pragma unroll
      for (int o = 1; o < 16; o <<= 1) m = fmaxf(m, __shfl_xor(m, o));
      if (cc == 0) redw[w][fm * 16 + r4 + i] = m;
    }
  __syncthreads();
  if (t < 64) {
    float g = redw[0][t];
#pragma unroll
    for (int ww = 1; ww < 6; ww++) g = fmaxf(g, redw[ww][t]);
    rowv[t] = g;
  }
  __syncthreads();

  // phase B+C: e = ratio*(exp(dd-diag-gm)+eps), store UNnormalized bf16 to
  // qfs with XOR-swizzled col.
#pragma unroll
  for (int fm = 0; fm < 4; fm++)
#pragma unroll
    for (int i = 0; i < 4; i++) {
      int row = fm * 16 + r4 + i;
      float gm = rowv[row];
      float dg = sdg[row];
      int swz = ((row >> 3) & 1) << 4;
#pragma unroll
      for (int fn = 0; fn < 3; fn++) {
        float e = 0.06131389f * (__expf(acc[fm][fn][i] * sc - dg - gm) + 1e-4f);
        int col = (wn + fn * 16 + cc) ^ swz;
        dl[row * 296 + col] = f2b(e);
      }
    }
  // ctx into cts[64][296] (base 18944)
#pragma unroll
  for (int j = 0; j < 6; j++) {
    int slot = j * 384 + t;
    *(v8s*)&dl[18944 + (slot / 36) * 296 + (slot % 36) * 8] = creg[j];
  }
  __syncthreads();

  // phase D: o_raw = e @ ctx; denom = e @ ksumb (extra MFMA column).
  if (w < 4) {
    v4f oacc[4] = {};
    v4f dacc = {};
    const int arow = w * 16 + rr;
    const int aswz = ((arow >> 3) & 1) << 4;
    for (int kk = 0; kk < 9; kk++) {
      v8s aq = *(const v8s*)&dl[arow * 296 + ((kk * 32 + kc) ^ aswz)];
      mfma_bf16(dacc, aq, kfrag[kk]);
#pragma unroll
      for (int et = 0; et < 4; et++) {
        v8s bc = *(const v8s*)&dl[18944 + (et * 16 + rr) * 296 + kk * 32 + kc];
        mfma_bf16(oacc[et], aq, bc);
      }
    }
    __builtin_amdgcn_sched_barrier(0);
    asm volatile("s_nop 7\ns_nop 7\ns_nop 7");
    __builtin_amdgcn_sched_barrier(0);
    const int b_ = bh >> 3, h_ = bh & 7;
    float dinv[4];
#pragma unroll
    for (int i = 0; i < 4; i++) {
      float dn = __shfl(dacc[i], lane & 48);   // col-0 lane of this row quad
      dinv[i] = 1.0f / dn;
    }
#pragma unroll
    for (int et = 0; et < 4; et++)
#pragma unroll
      for (int i = 0; i < 4; i++) {
        int n = tiM + w * 16 + r4 + i;
        obuf[((long long)(b_ * N_SEQ + n)) * 512 + h_ * 64 + et * 16 + cc] =
            f2b(oacc[et][i] * dinv[i]);
      }
  }
}

// ---------------------------------------------------------------------------
__global__ void ln_kernel(const float* __restrict__ x, const float* __restrict__ g,
                          const float* __restrict__ b, void* __restrict__ out)
{
  const int row = blockIdx.x * 4 + (threadIdx.x >> 6);
  const int lane = threadIdx.x & 63;
  const float* xr = x + (long long)row * D_MODEL + lane * 8;
  v4f v0 = *(const v4f*)xr;
  v4f v1 = *(const v4f*)(xr + 4);
  float s = v0[0] + v0[1] + v0[2] + v0[3] + v1[0] + v1[1] + v1[2] + v1[3];
  float sq = v0[0]*v0[0] + v0[1]*v0[1] + v0[2]*v0[2] + v0[3]*v0[3]
           + v1[0]*v1[0] + v1[1]*v1[1] + v1[2]*v1[2] + v1[3]*v1[3];
  s = wave_sum(s);
  sq = wave_sum(sq);
  float mu = s * (1.0f / D_MODEL);
  float var = sq * (1.0f / D_MODEL) - mu * mu;
  float rstd = rsqrtf(var + 1e-5f);
  v4f g0 = *(const v4f*)(g + lane * 8), g1 = *(const v4f*)(g + lane * 8 + 4);
  v4f bb0 = *(const v4f*)(b + lane * 8), bb1 = *(const v4f*)(b + lane * 8 + 4);
  float y[8];
#pragma unroll
  for (int j = 0; j < 4; j++) y[j] = (v0[j] - mu) * rstd * g0[j] + bb0[j];
#pragma unroll
  for (int j = 0; j < 4; j++) y[4 + j] = (v1[j] - mu) * rstd * g1[j] + bb1[j];
  u16* op = (u16*)out + (long long)row * D_MODEL + lane * 8;
  alignas(16) u16 tmp[8];
#pragma unroll
  for (int j = 0; j < 8; j++) tmp[j] = f2b(y[j]);
  *(v8s*)op = *(v8s*)tmp;
}

__global__ void posadd(const float* __restrict__ xin, float* __restrict__ x)
{
  long long i = (long long)blockIdx.x * 256 + threadIdx.x;
  int d = (int)(i & 511);
  int n = (int)((i >> 9) & 2047);
  int j = d & 255;
  float sarg = (float)n * expf(-0.035977892f * (float)j);
  float pe = (d < 256) ? sinf(sarg) : cosf(sarg);
  x[i] = xin[i] + pe;
}

__global__ void rotab(float* __restrict__ ts, float* __restrict__ tc)
{
  int i = blockIdx.x * 64 + threadIdx.x;  // 2048*32
  int n = i >> 5, j = i & 31;
  float sarg = (float)n * expf(-0.28782314f * (float)j);
  float s, c;
  sincosf(sarg, &s, &c);
  ts[i] = s;
  tc[i] = c;
}

// ---------------------------------------------------------------------------
// rotvt: fused rotary(q,k)+diag + v-transpose; also resets kmaxu (block 0).
// ---------------------------------------------------------------------------
__global__ void __launch_bounds__(256)
rotvt(const u16* __restrict__ qkv,
      const float* __restrict__ ts, const float* __restrict__ tc,
      u16* __restrict__ qr, u16* __restrict__ kr, u16* __restrict__ vT,
      float* __restrict__ dq, float* __restrict__ dk,
      unsigned int* __restrict__ kmaxu)
{
  __shared__ u16 st[64][72];
  const int bid = blockIdx.x;   // b*256 + h*32 + nt
  const int nt = bid & 31;
  const int h = (bid >> 5) & 7;
  const int b = bid >> 8;
  const int t = threadIdx.x;
  if (bid == 0 && t == 0) kmaxu[0] = 0u;
  const int r = t >> 3;
  const int cg = t & 7;
#pragma unroll
  for (int it = 0; it < 2; ++it) {
    const int nl = it * 32 + r;
    const int n = nt * 64 + nl;
    const long long src = ((long long)(b * N_SEQ + n)) * 1536 + h * 64 + cg * 8;
    v8s q8 = *(const v8s*)(qkv + src);
    v8s k8 = *(const v8s*)(qkv + src + 512);
    v8s v8 = *(const v8s*)(qkv + src + 1024);
    v4f sn = *(const v4f*)(ts + n * 32 + cg * 4);
    v4f cn = *(const v4f*)(tc + n * 32 + cg * 4);
    alignas(16) u16 qo[8], ko[8];
    float q2 = 0.0f, k2 = 0.0f;
#pragma unroll
    for (int j = 0; j < 4; j++) {
      float qe = b2f((u16)q8[2 * j]), qoe = b2f((u16)q8[2 * j + 1]);
      float ke = b2f((u16)k8[2 * j]), koe = b2f((u16)k8[2 * j + 1]);
      float c = cn[j], s = sn[j];
      float q0 = qe * c - qoe * s, q1 = qoe * c + qe * s;
      float k0 = ke * c - koe * s, k1 = koe * c + ke * s;
      qo[2 * j] = f2b(q0); qo[2 * j + 1] = f2b(q1);
      ko[2 * j] = f2b(k0); ko[2 * j + 1] = f2b(k1);
      q2 += q0 * q0 + q1 * q1;
      k2 += k0 * k0 + k1 * k1;
    }
    q2 += __shfl_xor(q2, 1); q2 += __shfl_xor(q2, 2); q2 += __shfl_xor(q2, 4);
    k2 += __shfl_xor(k2, 1); k2 += __shfl_xor(k2, 2); k2 += __shfl_xor(k2, 4);
    const long long rowidx = (long long)(b * 8 + h) * N_SEQ + n;
    if (cg == 0) {
      dq[rowidx] = q2 * 0.0625f;
      dk[rowidx] = k2 * 0.0625f;
    }
    *(v8s*)(qr + rowidx * 64 + cg * 8) = *(v8s*)qo;
    *(v8s*)(kr + rowidx * 64 + cg * 8) = *(v8s*)ko;
    *(v8s*)&st[nl][cg * 8] = v8;
  }
  __syncthreads();
  const int r2 = t >> 2, c2 = (t & 3) << 4;
  alignas(16) u16 tmp[16];
#pragma unroll
  for (int jj = 0; jj < 16; jj++) tmp[jj] = st[c2 + jj][r2];
  const long long dst = ((long long)((b * 8 + h) * 64 + r2)) * N_SEQ + nt * 64 + c2;
  *(v8s*)(vT + dst) = *(v8s*)&tmp[0];
  *(v8s*)(vT + dst + 8) = *(v8s*)&tmp[8];
}

__global__ void wtrans(const float* __restrict__ src, u16* __restrict__ dst,
                       int Ks, int Ns, long long sSrc, long long sDst)
{
  int l = blockIdx.z;
  src += (long long)l * sSrc;
  dst += (long long)l * sDst;
  int n0 = blockIdx.x << 6, k0 = blockIdx.y << 6;
  __shared__ float st[64][68];
  int t = threadIdx.x;
  int r = t >> 2, c = (t & 3) << 4;
  const float* sp = src + (long long)(k0 + r) * Ns + n0 + c;
#pragma unroll
  for (int jj = 0; jj < 16; jj += 4) *(v4f*)&st[r][c + jj] = *(const v4f*)(sp + jj);
  __syncthreads();
  alignas(16) u16 tmp[16];
#pragma unroll
  for (int jj = 0; jj < 16; jj++) tmp[jj] = f2b(st[c + jj][r]);
  u16* dp = dst + (long long)(n0 + r) * Ks + k0 + c;
  *(v8s*)(dp) = *(v8s*)&tmp[0];
  *(v8s*)(dp + 8) = *(v8s*)&tmp[8];
}

__global__ void projconv(const float* __restrict__ proj, u16* __restrict__ out)
{
  int i = blockIdx.x * 256 + threadIdx.x;  // 6*384*64
  int dh = i & 63;
  int m = (i >> 6) % M_ALLOC;
  int l = i / (M_ALLOC * 64);
  float v = (m < M_FEAT) ? proj[((long long)l * M_FEAT + m) * 64 + dh] : 0.0f;
  out[i] = f2b(v);
}

// reduce split-K ctx partials (4, stride M_PAD) + transpose -> ctxT bf16
__global__ void ctxred(const float* __restrict__ part, u16* __restrict__ ctxT)
{
  int bh = blockIdx.y;
  int m0 = blockIdx.x << 6;   // 5 tiles
  __shared__ float st[64][65];
  int t = threadIdx.x;
  int r = t >> 2, c = (t & 3) << 4;
  int m = m0 + r;
  v4f s[4] = {};
  if (m < M_PAD) {
    for (int ks = 0; ks < 4; ks++) {
      const float* p = part + (((long long)bh * 4 + ks) * M_PAD + m) * 64 + c;
#pragma unroll
      for (int j = 0; j < 4; j++) s[j] += *(const v4f*)(p + j * 4);
    }
  }
#pragma unroll
  for (int j = 0; j < 4; j++)
#pragma unroll
    for (int e = 0; e < 4; e++) st[r][c + j * 4 + e] = s[j][e];
  __syncthreads();
  int e = t >> 2, mc = (t & 3) << 4;
  if (m0 + mc < M_PAD) {
    alignas(16) u16 tmp[16];
#pragma unroll
    for (int j = 0; j < 16; j++) tmp[j] = f2b(st[mc + j][e]);
    u16* op = ctxT + ((long long)bh * 64 + e) * M_PAD + m0 + mc;
    *(v8s*)op = *(v8s*)&tmp[0];
    *(v8s*)(op + 8) = *(v8s*)&tmp[8];
  }
}

// ---------------------------------------------------------------------------
extern "C" void kernel_launch(void* const* d_in, const int* in_sizes, int n_in,
                              void* d_out, int out_size, void* d_ws, size_t ws_size,
                              hipStream_t stream)
{
  const float* x_in = (const float*)d_in[0];
  const float* Wq  = (const float*)d_in[1];
  const float* Wk  = (const float*)d_in[2];
  const float* Wv  = (const float*)d_in[3];
  const float* Wo  = (const float*)d_in[4];
  const float* Pr  = (const float*)d_in[5];
  const float* ln1g = (const float*)d_in[6];
  const float* ln1b = (const float*)d_in[7];
  const float* W1  = (const float*)d_in[8];
  const float* b1  = (const float*)d_in[9];
  const float* W2  = (const float*)d_in[10];
  const float* b2  = (const float*)d_in[11];
  const float* ln2g = (const float*)d_in[12];
  const float* ln2b = (const float*)d_in[13];
  const float* lnfg = (const float*)d_in[14];
  const float* lnfb = (const float*)d_in[15];

  hipFuncSetAttribute(reinterpret_cast<const void*>(&gemm4s<0, 1, 512>),
                      hipFuncAttributeMaxDynamicSharedMemorySize, 81920);
  hipFuncSetAttribute(reinterpret_cast<const void*>(&gemm4s<3, 1, 512>),
                      hipFuncAttributeMaxDynamicSharedMemorySize, 81920);
  hipFuncSetAttribute(reinterpret_cast<const void*>(&gemm4s<5, 2, 2048>),
                      hipFuncAttributeMaxDynamicSharedMemorySize, 81920);
  hipFuncSetAttribute(reinterpret_cast<const void*>(&ddq_qf_o),
                      hipFuncAttributeMaxDynamicSharedMemorySize, 75776);

  char* ws = (char*)d_ws;
  size_t off = 0;
  auto alloc = [&](size_t bytes) -> void* {
    void* p = ws + off;
    off = (off + bytes + 255) & ~(size_t)255;
    return p;
  };

  float* x      = (float*)alloc((size_t)ROWS * D_MODEL * 4);
  float* tsin   = (float*)alloc((size_t)N_SEQ * 32 * 4);
  float* tcos   = (float*)alloc((size_t)N_SEQ * 32 * 4);
  u16*   wqkvT  = (u16*)alloc((size_t)N_LAYER * 1536 * 512 * 2);
  u16*   woT    = (u16*)alloc((size_t)N_LAYER * 512 * 512 * 2);
  u16*   w1T    = (u16*)alloc((size_t)N_LAYER * 2048 * 512 * 2);
  u16*   w2T    = (u16*)alloc((size_t)N_LAYER * 512 * 2048 * 2);
  u16*   projT  = (u16*)alloc((size_t)N_LAYER * M_ALLOC * 64 * 2);
  u16*   hbuf   = (u16*)alloc((size_t)ROWS * D_MODEL * 2);
  u16*   obuf   = (u16*)alloc((size_t)ROWS * D_MODEL * 2);
  float* big    = (float*)alloc((size_t)32 * N_SEQ * M_PAD * 4);   // qkv_pre bf16 / ff bf16
  u16*   qrbuf  = (u16*)alloc((size_t)BHN * 64 * 2);
  u16*   krbuf  = (u16*)alloc((size_t)BHN * 64 * 2);
  u16*   vTbuf  = (u16*)alloc((size_t)BHN * 64 * 2);
  float* diagq  = (float*)alloc((size_t)BHN * 4);
  float* diagk  = (float*)alloc((size_t)BHN * 4);
  unsigned int* kmaxu = (unsigned int*)alloc(256);
  u16*   kfT    = (u16*)alloc((size_t)32 * M_ALLOC * N_SEQ * 2);
  float* part   = (float*)alloc((size_t)32 * 8 * M_PAD * 64 * 4);  // kept at 8-slot size (no layout shift)
  float* kspart = (float*)alloc((size_t)32 * M_PAD * 32 * 4);
  u16*   ctxT   = (u16*)alloc((size_t)32 * 64 * M_PAD * 2);
  float* ksum   = (float*)alloc((size_t)32 * M_PAD * 4);
  u16*   ksumb  = (u16*)alloc((size_t)32 * M_PAD * 2);
  (void)alloc(1 << 20);  // guard region for benign OOB tile reads
  (void)ws_size; (void)in_sizes; (void)n_in; (void)out_size;
  // FF2 split-K partials (2 x 16 MB) alias kfT: kfT is dead by FF2 time each
  // layer; both regions are rewritten next layer.
  float* ff2part = (float*)kfT;

  // ---- setup ----
  posadd<<<16384, 256, 0, stream>>>(x_in, x);
  rotab<<<1024, 64, 0, stream>>>(tsin, tcos);
  wtrans<<<dim3(8, 8, 6), 256, 0, stream>>>(Wq, wqkvT, 512, 512, 512LL * 512, 1536LL * 512);
  wtrans<<<dim3(8, 8, 6), 256, 0, stream>>>(Wk, wqkvT + 512LL * 512, 512, 512, 512LL * 512, 1536LL * 512);
  wtrans<<<dim3(8, 8, 6), 256, 0, stream>>>(Wv, wqkvT + 1024LL * 512, 512, 512, 512LL * 512, 1536LL * 512);
  wtrans<<<dim3(8, 8, 6), 256, 0, stream>>>(Wo, woT, 512, 512, 512LL * 512, 512LL * 512);
  wtrans<<<dim3(32, 8, 6), 256, 0, stream>>>(W1, w1T, 512, 2048, 512LL * 2048, 2048LL * 512);
  wtrans<<<dim3(8, 32, 6), 256, 0, stream>>>(W2, w2T, 2048, 512, 2048LL * 512, 512LL * 2048);
  projconv<<<(N_LAYER * M_ALLOC * 64) / 256, 256, 0, stream>>>(Pr, projT);

  // LN1 for layer 0 (later layers get it fused into ff2red_ln)
  ln_kernel<<<ROWS / 4, 256, 0, stream>>>(x, ln1g, ln1b, hbuf);

  for (int l = 0; l < N_LAYER; l++) {
    const u16* wq = wqkvT + (long long)l * 1536 * 512;
    const u16* wo = woT + (long long)l * 512 * 512;
    const u16* w1 = w1T + (long long)l * 2048 * 512;
    const u16* w2 = w2T + (long long)l * 512 * 2048;
    const u16* pj = projT + (long long)l * M_ALLOC * 64;

    // qkv_pre = h @ Wqkv^T  (8192 x 1536, K=512)
    gemm4s<0, 1, 512><<<dim3(64, 6), 512, 81920, stream>>>(hbuf, wq, big, nullptr, 1536);
    // fused rotary + diag + v-transpose (+ kmax reset)
    rotvt<<<1024, 256, 0, stream>>>((u16*)big, tsin, tcos, qrbuf, krbuf, vTbuf,
                                    diagq, diagk, kmaxu);
    // pass A: global k-max only (no dd store)
    gemm2<7, 128, 1><<<dim3(512, 3, 1), 256, 0, stream>>>(krbuf, pj, nullptr, nullptr,
        64, M_PAD, 0, 0, 0, 0.35355339f, M_PAD, BHN, kmaxu);
    // pass B: recompute + fused exp -> kfT + ksum partials
    kf_gemm<<<dim3(32, 1, 32), 384, 0, stream>>>(krbuf, pj, diagk, kmaxu, kfT, kspart);
    ksumred<<<(32 * M_PAD + 255) / 256, 256, 0, stream>>>(kspart, ksum, ksumb);
    // ctx = kf^T @ v  split-K=4 (partials stride M_PAD)
    gemm2<5, 64, 4><<<dim3(3, 1, 128), 256, 0, stream>>>(kfT, vTbuf, part, nullptr,
        2048, 64, (long long)M_ALLOC * N_SEQ, 64LL * N_SEQ, 0, 1.0f, 64, M_PAD, nullptr);
    ctxred<<<dim3(5, 32), 256, 0, stream>>>(part, ctxT);
    // fused dd_q -> e (LDS) -> {o_raw, denom} MFMA -> o scatter
    ddq_qf_o<<<dim3(32, 1, 32), 384, 75776, stream>>>(qrbuf, pj, diagq, ksumb, ctxT, obuf);
    // x += o @ Wo^T
    gemm_small<2, 512><<<dim3(128, 8, 1), 256, 0, stream>>>(obuf, wo, x, nullptr,
        512, 0, 0);
    // LN2 -> h
    ln_kernel<<<ROWS / 4, 256, 0, stream>>>(x, ln2g + l * 512, ln2b + l * 512, hbuf);
    // ff = gelu(h @ W1^T + b1)
    gemm4s<3, 1, 512><<<dim3(64, 8), 512, 81920, stream>>>(hbuf, w1, big,
        b1 + (long long)l * 2048, 2048);
    // ff2 partials = ff @ W2^T  [split-K=2]
    gemm4s<5, 2, 2048><<<dim3(64, 2, 2), 512, 81920, stream>>>((u16*)big, w2, ff2part,
        nullptr, 512);
    // x += sum(partials) + b2; fused LN (next layer's LN1, or final LN -> d_out)
    if (l < N_LAYER - 1) {
      ff2red_ln<false, 2><<<2048, 256, 0, stream>>>(ff2part, b2 + (long long)l * 512, x,
          ln1g + (long long)(l + 1) * 512, ln1b + (long long)(l + 1) * 512, hbuf);
    } else {
      ff2red_ln<true, 2><<<2048, 256, 0, stream>>>(ff2part, b2 + (long long)l * 512, x,
          lnfg, lnfb, d_out);
    }
  }
}

// Round 22
// 1286.573 us; speedup vs baseline: 1.0270x; 1.0120x over previous
//
#include <hip/hip_runtime.h>
#include <hip/hip_bf16.h>
#include <cstdint>

typedef float v4f __attribute__((ext_vector_type(4)));
typedef short v8s __attribute__((ext_vector_type(8)));
typedef unsigned short u16;

#define N_SEQ 2048
#define D_MODEL 512
#define N_LAYER 6
#define N_HEAD 8
#define D_HEAD 64
#define M_FEAT 266
#define M_PAD 288
#define M_ALLOC 384
#define FF_DIM 2048
#define BATCH 4
#define ROWS 8192
#define BHN 65536   // B*H*N

__device__ __forceinline__ float b2f(u16 u) {
  return __uint_as_float(((uint32_t)u) << 16);
}
__device__ __forceinline__ u16 f2b(float f) {
  union { __hip_bfloat16 h; u16 u; } c;
  c.h = __float2bfloat16(f);
  return c.u;
}
__device__ __forceinline__ float wave_sum(float v) {
#pragma unroll
  for (int o = 1; o < 64; o <<= 1) v += __shfl_xor(v, o);
  return v;
}
__device__ __forceinline__ float wave_max(float v) {
#pragma unroll
  for (int o = 1; o < 64; o <<= 1) v = fmaxf(v, __shfl_xor(v, o));
  return v;
}

// exact-erf gelu via Abramowitz-Stegun 7.1.26 (|erf err| <= 1.5e-7)
__device__ __forceinline__ float gelu_f(float x) {
  float ax = fabsf(x) * 0.70710678118f;
  float tt = __builtin_amdgcn_rcpf(fmaf(0.3275911f, ax, 1.0f));
  float poly = tt * fmaf(tt, fmaf(tt, fmaf(tt, fmaf(tt, 1.061405429f, -1.453152027f),
                                           1.421413741f), -0.284496736f), 0.254829592f);
  float er = 1.0f - poly * __expf(-ax * ax);
  er = copysignf(er, x);
  return 0.5f * x * (1.0f + er);
}

__device__ __forceinline__ void mfma_bf16(v4f& d, v8s a, v8s b) {
  asm volatile("v_mfma_f32_16x16x32_bf16 %0, %1, %2, %0" : "+v"(d) : "v"(a), "v"(b));
}

// async global->LDS, 16B per lane. LDS dest must be wave-linear (base + lane*16).
__device__ __forceinline__ void async16(const u16* g, u16* l) {
  __builtin_amdgcn_global_load_lds(
      (const __attribute__((address_space(1))) uint32_t*)g,
      (__attribute__((address_space(3))) uint32_t*)l, 16, 0, 0);
}

// ---------------------------------------------------------------------------
// gemm4s: 128x256 tile, BK=32, 512 threads (8 waves 2Mx4N, 64x64 each).
// Asymmetric dual ring: A 4 slots, B 3 slots; counted vmcnt(4). 80KB LDS.
// KTOT is compile-time -> K-loop FULLY UNROLLED: slot indices, staging
// branches and vmcnt selection all constant-fold.
// EPI: 0 = bf16 out; 3 = bf16 gelu(acc + bias); 5 = f32 split partial.
// ---------------------------------------------------------------------------
template <int EPI, int KSPLIT, int KTOT>
__global__ void __launch_bounds__(512, 4)
gemm4s(const u16* __restrict__ A, const u16* __restrict__ B,
       void* __restrict__ Cv, const float* __restrict__ bias,
       int ldc)
{
  extern __shared__ u16 lds[];
  const int t = threadIdx.x;
  const int lane = t & 63;
  const int w = t >> 6;
  const int wm = w >> 2;
  const int wn = w & 3;
  const int tiM = blockIdx.x << 7, tiN = blockIdx.y << 8;
  const int ks = (KSPLIT > 1) ? blockIdx.z : 0;
  constexpr int kchunk = KTOT / KSPLIT;
  constexpr int NT = kchunk >> 5;
  static_assert(NT >= 4, "pipeline needs >= 4 K-tiles");

  const int rr = lane & 15;
  const int kq = (lane >> 4) << 3;
  const int sw = ((rr >> 1) & 3) << 3;
  const int cr = kq ^ sw;

  const int srow = t >> 2;
  const int scol = (((t & 3) ^ ((srow >> 1) & 3)) << 3);
  const u16* Abase = A + (long long)(tiM + srow) * KTOT + scol + (long long)ks * kchunk;
  const u16* Bbase = B + (long long)(tiN + srow) * KTOT + scol + (long long)ks * kchunk;
  constexpr long long r128 = 128LL * KTOT;

  v4f acc[4][4] = {};

  auto stageA = [&](int s, int kt) {
    async16(Abase + (long long)kt * 32, &lds[s * 4096 + t * 8]);
  };
  auto stageB = [&](int s, int kt) {
    u16* d = &lds[16384 + s * 8192 + t * 8];
    async16(Bbase + (long long)kt * 32, d);
    async16(Bbase + (long long)kt * 32 + r128, d + 4096);
  };

  stageB(0, 0);
  stageA(0, 0);
  stageB(1, 1);
  stageA(1, 1);
  stageA(2, 2);
  asm volatile("s_waitcnt vmcnt(4)" ::: "memory");
  __builtin_amdgcn_s_barrier();

#pragma unroll
  for (int kt = 0; kt < NT; ++kt) {
    const int ab = (kt & 3) * 4096;          // compile-time per unrolled iter
    const int bb = 16384 + (kt % 3) * 8192;  // compile-time per unrolled iter
    if (kt + 2 < NT) stageB((kt + 2) % 3, kt + 2);
    if (kt + 3 < NT) stageA((kt + 3) & 3, kt + 3);
    v8s af[4], bf[4];
#pragma unroll
    for (int i = 0; i < 4; i++) {
      af[i] = *(const v8s*)&lds[ab + (wm * 64 + i * 16 + rr) * 32 + cr];
      bf[i] = *(const v8s*)&lds[bb + (wn * 64 + i * 16 + rr) * 32 + cr];
    }
    __builtin_amdgcn_s_setprio(1);
#pragma unroll
    for (int m = 0; m < 4; m++)
#pragma unroll
      for (int n = 0; n < 4; n++) mfma_bf16(acc[m][n], af[m], bf[n]);
    __builtin_amdgcn_s_setprio(0);
    if (kt + 1 < NT) {
      if (kt + 3 < NT)      asm volatile("s_waitcnt vmcnt(4)" ::: "memory");
      else if (kt + 2 < NT) asm volatile("s_waitcnt vmcnt(3)" ::: "memory");
      else                  asm volatile("s_waitcnt vmcnt(0)" ::: "memory");
      __builtin_amdgcn_s_barrier();
    }
  }

  __builtin_amdgcn_sched_barrier(0);
  asm volatile("s_nop 7\ns_nop 7\ns_nop 7");
  __builtin_amdgcn_sched_barrier(0);

  const int r4 = (lane >> 4) << 2;
  const int cc = lane & 15;
#pragma unroll
  for (int mf = 0; mf < 4; mf++)
#pragma unroll
    for (int nf = 0; nf < 4; nf++)
#pragma unroll
      for (int i = 0; i < 4; i++) {
        int row = tiM + wm * 64 + mf * 16 + r4 + i;
        int col = tiN + wn * 64 + nf * 16 + cc;
        float v = acc[mf][nf][i];
        if (EPI == 0) {
          ((u16*)Cv)[(long long)row * ldc + col] = f2b(v);
        } else if (EPI == 3) {
          ((u16*)Cv)[(long long)row * ldc + col] = f2b(gelu_f(v + bias[col]));
        } else {  // EPI == 5: f32 split partial
          ((float*)Cv)[((long long)ks * ROWS + row) * ldc + col] = v;
        }
      }
}

// ---------------------------------------------------------------------------
// ff2red_ln: x_new = x + sum of NSPLIT FF2 partials + b2; then LN(x_new).
// ---------------------------------------------------------------------------
template <bool LAST, int NSPLIT>
__global__ void ff2red_ln(const float* __restrict__ part, const float* __restrict__ bias,
                          float* __restrict__ x, const float* __restrict__ g,
                          const float* __restrict__ bvec, void* __restrict__ out)
{
  const int row = blockIdx.x * 4 + (threadIdx.x >> 6);
  const int lane = threadIdx.x & 63;
  const long long base = (long long)row * D_MODEL + lane * 8;
  v4f s0 = {}, s1 = {};
#pragma unroll
  for (int ks = 0; ks < NSPLIT; ks++) {
    const float* p = part + (long long)ks * (ROWS * 512LL) + base;
    s0 += *(const v4f*)p;
    s1 += *(const v4f*)(p + 4);
  }
  v4f b0 = *(const v4f*)(bias + lane * 8);
  v4f b1 = *(const v4f*)(bias + lane * 8 + 4);
  v4f x0 = *(const v4f*)(x + base) + s0 + b0;
  v4f x1 = *(const v4f*)(x + base + 4) + s1 + b1;
  if (!LAST) {
    *(v4f*)(x + base) = x0;
    *(v4f*)(x + base + 4) = x1;
  }
  float s = x0[0] + x0[1] + x0[2] + x0[3] + x1[0] + x1[1] + x1[2] + x1[3];
  float sq = x0[0]*x0[0] + x0[1]*x0[1] + x0[2]*x0[2] + x0[3]*x0[3]
           + x1[0]*x1[0] + x1[1]*x1[1] + x1[2]*x1[2] + x1[3]*x1[3];
  s = wave_sum(s);
  sq = wave_sum(sq);
  float mu = s * (1.0f / D_MODEL);
  float var = sq * (1.0f / D_MODEL) - mu * mu;
  float rstd = rsqrtf(var + 1e-5f);
  v4f g0 = *(const v4f*)(g + lane * 8), g1 = *(const v4f*)(g + lane * 8 + 4);
  v4f bb0 = *(const v4f*)(bvec + lane * 8), bb1 = *(const v4f*)(bvec + lane * 8 + 4);
  float y[8];
#pragma unroll
  for (int j = 0; j < 4; j++) y[j] = (x0[j] - mu) * rstd * g0[j] + bb0[j];
#pragma unroll
  for (int j = 0; j < 4; j++) y[4 + j] = (x1[j] - mu) * rstd * g1[j] + bb1[j];
  if (LAST) {
    float* op = (float*)out + base;
    v4f o0 = {y[0], y[1], y[2], y[3]}, o1 = {y[4], y[5], y[6], y[7]};
    *(v4f*)op = o0;
    *(v4f*)(op + 4) = o1;
  } else {
    u16* op = (u16*)out + base;
    alignas(16) u16 tmp[8];
#pragma unroll
    for (int j = 0; j < 8; j++) tmp[j] = f2b(y[j]);
    *(v8s*)op = *(v8s*)tmp;
  }
}

// ---------------------------------------------------------------------------
// gemm2: BM=128, BN in {64,128}.
// EPI: 5 = f32 split-K partial (stride M_PAD); 7 = max-only + fused atomicMax
// ---------------------------------------------------------------------------
template <int EPI, int BN, int KSPLIT>
__global__ void __launch_bounds__(256, 4)
gemm2(const u16* __restrict__ A, const u16* __restrict__ B,
      void* __restrict__ Cv, const float* __restrict__ bias,
      int K, int ldc, long long sA, long long sB, long long sC,
      float scale, int Ncap, int Mcap, unsigned int* __restrict__ gmax)
{
  __shared__ u16 As[2][128 * 32];
  __shared__ u16 Bs[2][BN * 32];
  __shared__ float smax[4];
  const int zz = blockIdx.z;
  const int z = (KSPLIT > 1) ? zz / KSPLIT : zz;
  const int ks = (KSPLIT > 1) ? zz % KSPLIT : 0;
  const int kchunk = K / KSPLIT;
  const u16* Ag = A + (long long)z * sA + ks * kchunk;
  const u16* Bg = B + (long long)z * sB + ks * kchunk;
  const int t = threadIdx.x;
  const int lane = t & 63;
  const int w = t >> 6;
  constexpr int NF = BN / 32;
  const int wm = (w >> 1) << 6;
  const int wn = (w & 1) * (BN / 2);
  const int tiM = blockIdx.x << 7, tiN = blockIdx.y * BN;

  const int srow = t >> 2;
  const int scol = (t & 3) << 3;
  const u16* Ap = Ag + (long long)(tiM + srow) * K + scol;
  const u16* Bp = Bg + (long long)(tiN + srow) * K + scol;
  const long long rstride = 64LL * K;

  const int rr = lane & 15;
  const int kc = (lane >> 4) << 3;

  v4f acc[4][NF] = {};

  const int nk = kchunk >> 5;
  auto stage = [&](int buf, int k0) {
    async16(Ap + k0, &As[buf][t * 8]);
    async16(Ap + k0 + rstride, &As[buf][t * 8 + 2048]);
    async16(Bp + k0, &Bs[buf][t * 8]);
    if (BN == 128) async16(Bp + k0 + rstride, &Bs[buf][t * 8 + 2048]);
  };

  stage(0, 0);
  __syncthreads();
  int cur = 0;
  for (int kt = 0; kt < nk; ++kt) {
    if (kt + 1 < nk) stage(cur ^ 1, (kt + 1) << 5);
    v8s af[4], bf[NF];
#pragma unroll
    for (int i = 0; i < 4; i++) af[i] = *(const v8s*)&As[cur][(wm + rr + i * 16) * 32 + kc];
#pragma unroll
    for (int i = 0; i < NF; i++) bf[i] = *(const v8s*)&Bs[cur][(wn + rr + i * 16) * 32 + kc];
#pragma unroll
    for (int fm = 0; fm < 4; fm++)
#pragma unroll
      for (int fn = 0; fn < NF; fn++)
        mfma_bf16(acc[fm][fn], af[fm], bf[fn]);
    __syncthreads();
    cur ^= 1;
  }

  __builtin_amdgcn_sched_barrier(0);
  asm volatile("s_nop 7\ns_nop 7\ns_nop 7");
  __builtin_amdgcn_sched_barrier(0);

  const int r4 = (lane >> 4) << 2;
  const int cc = lane & 15;
  float lmax = -3e38f;
#pragma unroll
  for (int fm = 0; fm < 4; fm++)
#pragma unroll
    for (int fn = 0; fn < NF; fn++)
#pragma unroll
      for (int i = 0; i < 4; i++) {
        int row = tiM + wm + fm * 16 + r4 + i;
        int col = tiN + wn + fn * 16 + cc;
        float v = acc[fm][fn][i];
        if (EPI == 5) {
          if (row < Mcap && col < Ncap)
            ((float*)Cv)[((long long)zz * M_PAD + row) * 64 + col] = v;
        } else if (EPI == 7) {
          if (col < M_FEAT) lmax = fmaxf(lmax, v * scale);
        }
      }

  if (EPI == 7) {
    lmax = wave_max(lmax);
    if (lane == 0) smax[w] = lmax;
    __syncthreads();
    if (t == 0) {
      float m = fmaxf(fmaxf(smax[0], smax[1]), fmaxf(smax[2], smax[3]));
      unsigned int u = __float_as_uint(m);
      unsigned int key = (u & 0x80000000u) ? ~u : (u | 0x80000000u);
      atomicMax(gmax, key);
    }
  }
}

// ---------------------------------------------------------------------------
// kf_gemm: transposed K-feature GEMM + fused exp epilogue (dd never stored).
// ---------------------------------------------------------------------------
__global__ void __launch_bounds__(384, 3)
kf_gemm(const u16* __restrict__ kr, const u16* __restrict__ proj,
        const float* __restrict__ diagk, const unsigned int* __restrict__ kmax,
        u16* __restrict__ kfT, float* __restrict__ part)
{
  __shared__ u16 As[2][288 * 32];   // proj rows m
  __shared__ u16 Bs[2][64 * 32];    // k_rot rows n
  __shared__ float sdg[64];
  const int ntile = blockIdx.x;     // 0..31
  const int bh = blockIdx.z;        // 0..31
  const int n0 = ntile << 6;
  const int t = threadIdx.x;
  const int lane = t & 63;
  const int w = t >> 6;             // 0..5
  const u16* Bg = kr + (long long)bh * (N_SEQ * 64) + (long long)n0 * 64;
  const int rr = lane & 15, kc = (lane >> 4) << 3;

  if (t < 64) sdg[t] = diagk[(long long)bh * N_SEQ + n0 + t];
  unsigned int kk = kmax[0];
  const float km = (kk & 0x80000000u) ? __uint_as_float(kk ^ 0x80000000u)
                                      : __uint_as_float(~kk);

  v4f acc[3][4] = {};
  auto stage = [&](int buf, int k0) {
#pragma unroll
    for (int j = 0; j < 3; j++) {
      int idx = j * 384 + t;        // proj rows 0..287
      async16(proj + (long long)(idx >> 2) * 64 + ((idx & 3) << 3) + k0,
              &As[buf][j * 3072 + t * 8]);
    }
    if (t < 256) async16(Bg + (long long)(t >> 2) * 64 + ((t & 3) << 3) + k0,
                         &Bs[buf][t * 8]);
  };

  stage(0, 0);
  __syncthreads();
  for (int kt = 0; kt < 2; ++kt) {
    if (kt == 0) stage(1, 32);
    v8s af[3], bf[4];
#pragma unroll
    for (int i = 0; i < 3; i++) af[i] = *(const v8s*)&As[kt][(w * 48 + i * 16 + rr) * 32 + kc];
#pragma unroll
    for (int i = 0; i < 4; i++) bf[i] = *(const v8s*)&Bs[kt][(i * 16 + rr) * 32 + kc];
#pragma unroll
    for (int fm = 0; fm < 3; fm++)
#pragma unroll
      for (int fn = 0; fn < 4; fn++)
        mfma_bf16(acc[fm][fn], af[fm], bf[fn]);
    __syncthreads();
  }

  __builtin_amdgcn_sched_barrier(0);
  asm volatile("s_nop 7\ns_nop 7\ns_nop 7");
  __builtin_amdgcn_sched_barrier(0);

  const int r4 = (lane >> 4) << 2;
  const int cc = lane & 15;
  const float sc = 0.35355339f;

#pragma unroll
  for (int fm = 0; fm < 3; fm++)
#pragma unroll
    for (int i = 0; i < 4; i++) {
      int m = w * 48 + fm * 16 + r4 + i;
      float s = 0.0f;
#pragma unroll
      for (int fn = 0; fn < 4; fn++) {
        float dd = acc[fm][fn][i] * sc;
        float kf = (m < M_FEAT)
            ? 0.06131389f * (__expf(dd - sdg[fn * 16 + cc] - km) + 1e-4f) : 0.0f;
        acc[fm][fn][i] = kf;
        s += kf;
        kfT[((long long)bh * M_ALLOC + m) * N_SEQ + n0 + fn * 16 + cc] = f2b(kf);
      }
#pragma unroll
      for (int o = 1; o < 16; o <<= 1) s += __shfl_xor(s, o);
      if (cc == 0) part[((long long)bh * M_PAD + m) * 32 + ntile] = s;
    }
}

// ---------------------------------------------------------------------------
// gemm_small: BM=64, BN=64, BK=32, compile-time K (unrolled loop).
// EPI 2 = f32 residual += acc + bias.
// ---------------------------------------------------------------------------
template <int EPI, int K>
__global__ void __launch_bounds__(256, 6)
gemm_small(const u16* __restrict__ A, const u16* __restrict__ B,
           void* __restrict__ Cv, const float* __restrict__ bias,
           int ldc, long long sA, long long sB)
{
  __shared__ u16 As[2][64 * 32];
  __shared__ u16 Bs[2][64 * 32];
  const int z = blockIdx.z;
  const u16* Ag = A + (long long)z * sA;
  const u16* Bg = B + (long long)z * sB;
  const int t = threadIdx.x;
  const int lane = t & 63;
  const int w = t >> 6;
  const int wm = (w >> 1) << 5;
  const int wn = (w & 1) << 5;
  const int tiM = blockIdx.x << 6, tiN = blockIdx.y << 6;

  const int srow = t >> 2;
  const int scol = (t & 3) << 3;
  const u16* Ap = Ag + (long long)(tiM + srow) * K + scol;
  const u16* Bp = Bg + (long long)(tiN + srow) * K + scol;

  const int rr = lane & 15;
  const int kc = (lane >> 4) << 3;

  v4f acc[2][2] = {};

  constexpr int nk = K >> 5;
  auto stage = [&](int buf, int k0) {
    async16(Ap + k0, &As[buf][t * 8]);
    async16(Bp + k0, &Bs[buf][t * 8]);
  };

  stage(0, 0);
  __syncthreads();
#pragma unroll
  for (int kt = 0; kt < nk; ++kt) {
    const int cur = kt & 1;
    if (kt + 1 < nk) stage(cur ^ 1, (kt + 1) << 5);
    v8s af[2], bf[2];
#pragma unroll
    for (int i = 0; i < 2; i++) af[i] = *(const v8s*)&As[cur][(wm + rr + i * 16) * 32 + kc];
#pragma unroll
    for (int i = 0; i < 2; i++) bf[i] = *(const v8s*)&Bs[cur][(wn + rr + i * 16) * 32 + kc];
#pragma unroll
    for (int fm = 0; fm < 2; fm++)
#pragma unroll
      for (int fn = 0; fn < 2; fn++)
        mfma_bf16(acc[fm][fn], af[fm], bf[fn]);
    __syncthreads();
  }

  __builtin_amdgcn_sched_barrier(0);
  asm volatile("s_nop 7\ns_nop 7\ns_nop 7");
  __builtin_amdgcn_sched_barrier(0);

  const int r4 = (lane >> 4) << 2;
  const int cc = lane & 15;
#pragma unroll
  for (int fm = 0; fm < 2; fm++)
#pragma unroll
    for (int fn = 0; fn < 2; fn++)
#pragma unroll
      for (int i = 0; i < 4; i++) {
        int row = tiM + wm + fm * 16 + r4 + i;
        int col = tiN + wn + fn * 16 + cc;
        float v = acc[fm][fn][i];
        long long idx = (long long)row * ldc + col;
        float bb = bias ? bias[col] : 0.0f;
        ((float*)Cv)[idx] += v + bb;
      }
}

// ---------------------------------------------------------------------------
// ddq_qf_o: dd_q GEMM -> row-max -> exp (UNnormalized e to LDS, XOR-swizzled)
// -> fused {o_raw = e @ ctx^T, denom = e @ ksumb} via MFMA -> o = o_raw/denom
// -> head-scatter. qf never hits global.
// ---------------------------------------------------------------------------
__global__ void __launch_bounds__(384, 3)
ddq_qf_o(const u16* __restrict__ qr, const u16* __restrict__ proj,
         const float* __restrict__ diag, const u16* __restrict__ ksumb,
         const u16* __restrict__ ctxT, u16* __restrict__ obuf)
{
  extern __shared__ u16 dl[];
  __shared__ float redw[6][64];
  __shared__ float rowv[64];
  __shared__ float sdg[64];
  const int bh = blockIdx.z;
  const int tiM = blockIdx.x << 6;
  const int t = threadIdx.x;
  const int lane = t & 63;
  const int w = t >> 6;          // 0..5
  const u16* Ag = qr + (long long)bh * (N_SEQ * 64);
  const u16* Ap = Ag + (long long)(tiM + (t >> 2)) * 64 + ((t & 3) << 3);
  const int rr = lane & 15, kc = (lane >> 4) << 3;
  const int wn = w * 48;

  if (t < 64) sdg[t] = diag[(long long)bh * N_SEQ + tiM + t];

  v4f acc[4][3] = {};
  auto stage = [&](int buf, int k0) {
    if (t < 256) async16(Ap + k0, &dl[buf * 2048 + t * 8]);
#pragma unroll
    for (int j = 0; j < 3; j++) {
      int idx = j * 384 + t;
      async16(proj + (long long)(idx >> 2) * 64 + ((idx & 3) << 3) + k0,
              &dl[4096 + buf * 9216 + j * 3072 + t * 8]);
    }
  };

  stage(0, 0);
  __syncthreads();
  for (int kt = 0; kt < 2; ++kt) {
    if (kt == 0) stage(1, 32);
    v8s af[4], bf[3];
#pragma unroll
    for (int i = 0; i < 4; i++)
      af[i] = *(const v8s*)&dl[kt * 2048 + (rr + i * 16) * 32 + kc];
#pragma unroll
    for (int i = 0; i < 3; i++)
      bf[i] = *(const v8s*)&dl[4096 + kt * 9216 + (wn + i * 16 + rr) * 32 + kc];
#pragma unroll
    for (int fm = 0; fm < 4; fm++)
#pragma unroll
      for (int fn = 0; fn < 3; fn++)
        mfma_bf16(acc[fm][fn], af[fm], bf[fn]);
    __syncthreads();
  }

  __builtin_amdgcn_sched_barrier(0);
  asm volatile("s_nop 7\ns_nop 7\ns_nop 7");
  __builtin_amdgcn_sched_barrier(0);

  // early global loads: ctx tile + ksumb fragments (hide latency under softmax)
  v8s creg[6];
  const u16* cb = ctxT + (long long)bh * (64 * M_PAD);
#pragma unroll
  for (int j = 0; j < 6; j++) {
    int slot = j * 384 + t;       // row = slot/36, col8 = slot%36
    creg[j] = *(const v8s*)(cb + (slot / 36) * M_PAD + (slot % 36) * 8);
  }
  v8s kfrag[9];
  {
    const u16* kb = ksumb + bh * M_PAD;
    const v8s z = {};
#pragma unroll
    for (int kk = 0; kk < 9; kk++)
      kfrag[kk] = (rr == 0) ? *(const v8s*)(kb + kk * 32 + kc) : z;
  }

  const int r4 = (lane >> 4) << 2;
  const int cc = lane & 15;
  const float sc = 0.35355339f;

  // phase A: per-row max over valid cols (cross-wave for consistency)
#pragma unroll
  for (int fm = 0; fm < 4; fm++)
#pragma unroll
    for (int i = 0; i < 4; i++) {
      float m = -3e38f;
#pragma unroll
      for (int fn = 0; fn < 3; fn++) {
        int col = wn + fn * 16 + cc;
        float v = acc[fm][fn][i] * sc;
        if (col < M_FEAT) m = fmaxf(m, v);
      }
#pragma unroll
      for (int o = 1; o < 16; o <<= 1) m = fmaxf(m, __shfl_xor(m, o));
      if (cc == 0) redw[w][fm * 16 + r4 + i] = m;
    }
  __syncthreads();
  if (t < 64) {
    float g = redw[0][t];
#pragma unroll
    for (int ww = 1; ww < 6; ww++) g = fmaxf(g, redw[ww][t]);
    rowv[t] = g;
  }
  __syncthreads();

  // phase B+C: e = ratio*(exp(dd-diag-gm)+eps), store UNnormalized bf16 to
  // qfs with XOR-swizzled col.
#pragma unroll
  for (int fm = 0; fm < 4; fm++)
#pragma unroll
    for (int i = 0; i < 4; i++) {
      int row = fm * 16 + r4 + i;
      float gm = rowv[row];
      float dg = sdg[row];
      int swz = ((row >> 3) & 1) << 4;
#pragma unroll
      for (int fn = 0; fn < 3; fn++) {
        float e = 0.06131389f * (__expf(acc[fm][fn][i] * sc - dg - gm) + 1e-4f);
        int col = (wn + fn * 16 + cc) ^ swz;
        dl[row * 296 + col] = f2b(e);
      }
    }
  // ctx into cts[64][296] (base 18944)
#pragma unroll
  for (int j = 0; j < 6; j++) {
    int slot = j * 384 + t;
    *(v8s*)&dl[18944 + (slot / 36) * 296 + (slot % 36) * 8] = creg[j];
  }
  __syncthreads();

  // phase D: o_raw = e @ ctx; denom = e @ ksumb (extra MFMA column).
  if (w < 4) {
    v4f oacc[4] = {};
    v4f dacc = {};
    const int arow = w * 16 + rr;
    const int aswz = ((arow >> 3) & 1) << 4;
    for (int kk = 0; kk < 9; kk++) {
      v8s aq = *(const v8s*)&dl[arow * 296 + ((kk * 32 + kc) ^ aswz)];
      mfma_bf16(dacc, aq, kfrag[kk]);
#pragma unroll
      for (int et = 0; et < 4; et++) {
        v8s bc = *(const v8s*)&dl[18944 + (et * 16 + rr) * 296 + kk * 32 + kc];
        mfma_bf16(oacc[et], aq, bc);
      }
    }
    __builtin_amdgcn_sched_barrier(0);
    asm volatile("s_nop 7\ns_nop 7\ns_nop 7");
    __builtin_amdgcn_sched_barrier(0);
    const int b_ = bh >> 3, h_ = bh & 7;
    float dinv[4];
#pragma unroll
    for (int i = 0; i < 4; i++) {
      float dn = __shfl(dacc[i], lane & 48);   // col-0 lane of this row quad
      dinv[i] = 1.0f / dn;
    }
#pragma unroll
    for (int et = 0; et < 4; et++)
#pragma unroll
      for (int i = 0; i < 4; i++) {
        int n = tiM + w * 16 + r4 + i;
        obuf[((long long)(b_ * N_SEQ + n)) * 512 + h_ * 64 + et * 16 + cc] =
            f2b(oacc[et][i] * dinv[i]);
      }
  }
}

// ---------------------------------------------------------------------------
__global__ void ln_kernel(const float* __restrict__ x, const float* __restrict__ g,
                          const float* __restrict__ b, void* __restrict__ out)
{
  const int row = blockIdx.x * 4 + (threadIdx.x >> 6);
  const int lane = threadIdx.x & 63;
  const float* xr = x + (long long)row * D_MODEL + lane * 8;
  v4f v0 = *(const v4f*)xr;
  v4f v1 = *(const v4f*)(xr + 4);
  float s = v0[0] + v0[1] + v0[2] + v0[3] + v1[0] + v1[1] + v1[2] + v1[3];
  float sq = v0[0]*v0[0] + v0[1]*v0[1] + v0[2]*v0[2] + v0[3]*v0[3]
           + v1[0]*v1[0] + v1[1]*v1[1] + v1[2]*v1[2] + v1[3]*v1[3];
  s = wave_sum(s);
  sq = wave_sum(sq);
  float mu = s * (1.0f / D_MODEL);
  float var = sq * (1.0f / D_MODEL) - mu * mu;
  float rstd = rsqrtf(var + 1e-5f);
  v4f g0 = *(const v4f*)(g + lane * 8), g1 = *(const v4f*)(g + lane * 8 + 4);
  v4f bb0 = *(const v4f*)(b + lane * 8), bb1 = *(const v4f*)(b + lane * 8 + 4);
  float y[8];
#pragma unroll
  for (int j = 0; j < 4; j++) y[j] = (v0[j] - mu) * rstd * g0[j] + bb0[j];
#pragma unroll
  for (int j = 0; j < 4; j++) y[4 + j] = (v1[j] - mu) * rstd * g1[j] + bb1[j];
  u16* op = (u16*)out + (long long)row * D_MODEL + lane * 8;
  alignas(16) u16 tmp[8];
#pragma unroll
  for (int j = 0; j < 8; j++) tmp[j] = f2b(y[j]);
  *(v8s*)op = *(v8s*)tmp;
}

__global__ void posadd(const float* __restrict__ xin, float* __restrict__ x)
{
  long long i = (long long)blockIdx.x * 256 + threadIdx.x;
  int d = (int)(i & 511);
  int n = (int)((i >> 9) & 2047);
  int j = d & 255;
  float sarg = (float)n * expf(-0.035977892f * (float)j);
  float pe = (d < 256) ? sinf(sarg) : cosf(sarg);
  x[i] = xin[i] + pe;
}

__global__ void rotab(float* __restrict__ ts, float* __restrict__ tc)
{
  int i = blockIdx.x * 64 + threadIdx.x;  // 2048*32
  int n = i >> 5, j = i & 31;
  float sarg = (float)n * expf(-0.28782314f * (float)j);
  float s, c;
  sincosf(sarg, &s, &c);
  ts[i] = s;
  tc[i] = c;
}

// ---------------------------------------------------------------------------
// rotvt: fused rotary(q,k)+diag + v-transpose; also resets kmaxu (block 0).
// ---------------------------------------------------------------------------
__global__ void __launch_bounds__(256)
rotvt(const u16* __restrict__ qkv,
      const float* __restrict__ ts, const float* __restrict__ tc,
      u16* __restrict__ qr, u16* __restrict__ kr, u16* __restrict__ vT,
      float* __restrict__ dq, float* __restrict__ dk,
      unsigned int* __restrict__ kmaxu)
{
  __shared__ u16 st[64][72];
  const int bid = blockIdx.x;   // b*256 + h*32 + nt
  const int nt = bid & 31;
  const int h = (bid >> 5) & 7;
  const int b = bid >> 8;
  const int t = threadIdx.x;
  if (bid == 0 && t == 0) kmaxu[0] = 0u;
  const int r = t >> 3;
  const int cg = t & 7;
#pragma unroll
  for (int it = 0; it < 2; ++it) {
    const int nl = it * 32 + r;
    const int n = nt * 64 + nl;
    const long long src = ((long long)(b * N_SEQ + n)) * 1536 + h * 64 + cg * 8;
    v8s q8 = *(const v8s*)(qkv + src);
    v8s k8 = *(const v8s*)(qkv + src + 512);
    v8s v8 = *(const v8s*)(qkv + src + 1024);
    v4f sn = *(const v4f*)(ts + n * 32 + cg * 4);
    v4f cn = *(const v4f*)(tc + n * 32 + cg * 4);
    alignas(16) u16 qo[8], ko[8];
    float q2 = 0.0f, k2 = 0.0f;
#pragma unroll
    for (int j = 0; j < 4; j++) {
      float qe = b2f((u16)q8[2 * j]), qoe = b2f((u16)q8[2 * j + 1]);
      float ke = b2f((u16)k8[2 * j]), koe = b2f((u16)k8[2 * j + 1]);
      float c = cn[j], s = sn[j];
      float q0 = qe * c - qoe * s, q1 = qoe * c + qe * s;
      float k0 = ke * c - koe * s, k1 = koe * c + ke * s;
      qo[2 * j] = f2b(q0); qo[2 * j + 1] = f2b(q1);
      ko[2 * j] = f2b(k0); ko[2 * j + 1] = f2b(k1);
      q2 += q0 * q0 + q1 * q1;
      k2 += k0 * k0 + k1 * k1;
    }
    q2 += __shfl_xor(q2, 1); q2 += __shfl_xor(q2, 2); q2 += __shfl_xor(q2, 4);
    k2 += __shfl_xor(k2, 1); k2 += __shfl_xor(k2, 2); k2 += __shfl_xor(k2, 4);
    const long long rowidx = (long long)(b * 8 + h) * N_SEQ + n;
    if (cg == 0) {
      dq[rowidx] = q2 * 0.0625f;
      dk[rowidx] = k2 * 0.0625f;
    }
    *(v8s*)(qr + rowidx * 64 + cg * 8) = *(v8s*)qo;
    *(v8s*)(kr + rowidx * 64 + cg * 8) = *(v8s*)ko;
    *(v8s*)&st[nl][cg * 8] = v8;
  }
  __syncthreads();
  const int r2 = t >> 2, c2 = (t & 3) << 4;
  alignas(16) u16 tmp[16];
#pragma unroll
  for (int jj = 0; jj < 16; jj++) tmp[jj] = st[c2 + jj][r2];
  const long long dst = ((long long)((b * 8 + h) * 64 + r2)) * N_SEQ + nt * 64 + c2;
  *(v8s*)(vT + dst) = *(v8s*)&tmp[0];
  *(v8s*)(vT + dst + 8) = *(v8s*)&tmp[8];
}

__global__ void wtrans(const float* __restrict__ src, u16* __restrict__ dst,
                       int Ks, int Ns, long long sSrc, long long sDst)
{
  int l = blockIdx.z;
  src += (long long)l * sSrc;
  dst += (long long)l * sDst;
  int n0 = blockIdx.x << 6, k0 = blockIdx.y << 6;
  __shared__ float st[64][68];
  int t = threadIdx.x;
  int r = t >> 2, c = (t & 3) << 4;
  const float* sp = src + (long long)(k0 + r) * Ns + n0 + c;
#pragma unroll
  for (int jj = 0; jj < 16; jj += 4) *(v4f*)&st[r][c + jj] = *(const v4f*)(sp + jj);
  __syncthreads();
  alignas(16) u16 tmp[16];
#pragma unroll
  for (int jj = 0; jj < 16; jj++) tmp[jj] = f2b(st[c + jj][r]);
  u16* dp = dst + (long long)(n0 + r) * Ks + k0 + c;
  *(v8s*)(dp) = *(v8s*)&tmp[0];
  *(v8s*)(dp + 8) = *(v8s*)&tmp[8];
}

__global__ void projconv(const float* __restrict__ proj, u16* __restrict__ out)
{
  int i = blockIdx.x * 256 + threadIdx.x;  // 6*384*64
  int dh = i & 63;
  int m = (i >> 6) % M_ALLOC;
  int l = i / (M_ALLOC * 64);
  float v = (m < M_FEAT) ? proj[((long long)l * M_FEAT + m) * 64 + dh] : 0.0f;
  out[i] = f2b(v);
}

// reduce split-K ctx partials (4, stride M_PAD) + transpose -> ctxT bf16;
// ALSO reduces the kspart ksum partials for its 64 m-rows -> ksumb (each
// (bh,m) owned by exactly one block; kspart written upstream, ksumb read
// downstream in-stream -> no ordering hazard).
__global__ void ctxred(const float* __restrict__ part, u16* __restrict__ ctxT,
                       const float* __restrict__ kspart, u16* __restrict__ ksumb)
{
  int bh = blockIdx.y;
  int m0 = blockIdx.x << 6;   // 5 tiles
  __shared__ float st[64][65];
  int t = threadIdx.x;
  int r = t >> 2, c = (t & 3) << 4;
  int m = m0 + r;
  v4f s[4] = {};
  if (m < M_PAD) {
    for (int ks = 0; ks < 4; ks++) {
      const float* p = part + (((long long)bh * 4 + ks) * M_PAD + m) * 64 + c;
#pragma unroll
      for (int j = 0; j < 4; j++) s[j] += *(const v4f*)(p + j * 4);
    }
  }
#pragma unroll
  for (int j = 0; j < 4; j++)
#pragma unroll
    for (int e = 0; e < 4; e++) st[r][c + j * 4 + e] = s[j][e];
  // fused ksum reduce: thread t<64 owns row m0+t (same math as old ksumred)
  if (t < 64 && m0 + t < M_PAD) {
    const float* p = kspart + ((long long)bh * M_PAD + m0 + t) * 32;
    float ss = 0.0f;
#pragma unroll
    for (int j = 0; j < 32; j += 4) {
      v4f v = *(const v4f*)(p + j);
      ss += v[0] + v[1] + v[2] + v[3];
    }
    ksumb[bh * M_PAD + m0 + t] = f2b(ss);
  }
  __syncthreads();
  int e = t >> 2, mc = (t & 3) << 4;
  if (m0 + mc < M_PAD) {
    alignas(16) u16 tmp[16];
#pragma unroll
    for (int j = 0; j < 16; j++) tmp[j] = f2b(st[mc + j][e]);
    u16* op = ctxT + ((long long)bh * 64 + e) * M_PAD + m0 + mc;
    *(v8s*)op = *(v8s*)&tmp[0];
    *(v8s*)(op + 8) = *(v8s*)&tmp[8];
  }
}

// ---------------------------------------------------------------------------
extern "C" void kernel_launch(void* const* d_in, const int* in_sizes, int n_in,
                              void* d_out, int out_size, void* d_ws, size_t ws_size,
                              hipStream_t stream)
{
  const float* x_in = (const float*)d_in[0];
  const float* Wq  = (const float*)d_in[1];
  const float* Wk  = (const float*)d_in[2];
  const float* Wv  = (const float*)d_in[3];
  const float* Wo  = (const float*)d_in[4];
  const float* Pr  = (const float*)d_in[5];
  const float* ln1g = (const float*)d_in[6];
  const float* ln1b = (const float*)d_in[7];
  const float* W1  = (const float*)d_in[8];
  const float* b1  = (const float*)d_in[9];
  const float* W2  = (const float*)d_in[10];
  const float* b2  = (const float*)d_in[11];
  const float* ln2g = (const float*)d_in[12];
  const float* ln2b = (const float*)d_in[13];
  const float* lnfg = (const float*)d_in[14];
  const float* lnfb = (const float*)d_in[15];

  hipFuncSetAttribute(reinterpret_cast<const void*>(&gemm4s<0, 1, 512>),
                      hipFuncAttributeMaxDynamicSharedMemorySize, 81920);
  hipFuncSetAttribute(reinterpret_cast<const void*>(&gemm4s<3, 1, 512>),
                      hipFuncAttributeMaxDynamicSharedMemorySize, 81920);
  hipFuncSetAttribute(reinterpret_cast<const void*>(&gemm4s<5, 2, 2048>),
                      hipFuncAttributeMaxDynamicSharedMemorySize, 81920);
  hipFuncSetAttribute(reinterpret_cast<const void*>(&ddq_qf_o),
                      hipFuncAttributeMaxDynamicSharedMemorySize, 75776);

  char* ws = (char*)d_ws;
  size_t off = 0;
  auto alloc = [&](size_t bytes) -> void* {
    void* p = ws + off;
    off = (off + bytes + 255) & ~(size_t)255;
    return p;
  };

  float* x      = (float*)alloc((size_t)ROWS * D_MODEL * 4);
  float* tsin   = (float*)alloc((size_t)N_SEQ * 32 * 4);
  float* tcos   = (float*)alloc((size_t)N_SEQ * 32 * 4);
  u16*   wqkvT  = (u16*)alloc((size_t)N_LAYER * 1536 * 512 * 2);
  u16*   woT    = (u16*)alloc((size_t)N_LAYER * 512 * 512 * 2);
  u16*   w1T    = (u16*)alloc((size_t)N_LAYER * 2048 * 512 * 2);
  u16*   w2T    = (u16*)alloc((size_t)N_LAYER * 512 * 2048 * 2);
  u16*   projT  = (u16*)alloc((size_t)N_LAYER * M_ALLOC * 64 * 2);
  u16*   hbuf   = (u16*)alloc((size_t)ROWS * D_MODEL * 2);
  u16*   obuf   = (u16*)alloc((size_t)ROWS * D_MODEL * 2);
  float* big    = (float*)alloc((size_t)32 * N_SEQ * M_PAD * 4);   // qkv_pre bf16 / ff bf16
  u16*   qrbuf  = (u16*)alloc((size_t)BHN * 64 * 2);
  u16*   krbuf  = (u16*)alloc((size_t)BHN * 64 * 2);
  u16*   vTbuf  = (u16*)alloc((size_t)BHN * 64 * 2);
  float* diagq  = (float*)alloc((size_t)BHN * 4);
  float* diagk  = (float*)alloc((size_t)BHN * 4);
  unsigned int* kmaxu = (unsigned int*)alloc(256);
  u16*   kfT    = (u16*)alloc((size_t)32 * M_ALLOC * N_SEQ * 2);
  float* part   = (float*)alloc((size_t)32 * 8 * M_PAD * 64 * 4);  // kept at 8-slot size (no layout shift)
  float* kspart = (float*)alloc((size_t)32 * M_PAD * 32 * 4);
  u16*   ctxT   = (u16*)alloc((size_t)32 * 64 * M_PAD * 2);
  float* ksum   = (float*)alloc((size_t)32 * M_PAD * 4);           // dead; kept for layout parity
  u16*   ksumb  = (u16*)alloc((size_t)32 * M_PAD * 2);
  (void)alloc(1 << 20);  // guard region for benign OOB tile reads
  (void)ws_size; (void)in_sizes; (void)n_in; (void)out_size; (void)ksum;
  // FF2 split-K partials (2 x 16 MB) alias kfT: kfT is dead by FF2 time each
  // layer; both regions are rewritten next layer.
  float* ff2part = (float*)kfT;

  // ---- setup ----
  posadd<<<16384, 256, 0, stream>>>(x_in, x);
  rotab<<<1024, 64, 0, stream>>>(tsin, tcos);
  wtrans<<<dim3(8, 8, 6), 256, 0, stream>>>(Wq, wqkvT, 512, 512, 512LL * 512, 1536LL * 512);
  wtrans<<<dim3(8, 8, 6), 256, 0, stream>>>(Wk, wqkvT + 512LL * 512, 512, 512, 512LL * 512, 1536LL * 512);
  wtrans<<<dim3(8, 8, 6), 256, 0, stream>>>(Wv, wqkvT + 1024LL * 512, 512, 512, 512LL * 512, 1536LL * 512);
  wtrans<<<dim3(8, 8, 6), 256, 0, stream>>>(Wo, woT, 512, 512, 512LL * 512, 512LL * 512);
  wtrans<<<dim3(32, 8, 6), 256, 0, stream>>>(W1, w1T, 512, 2048, 512LL * 2048, 2048LL * 512);
  wtrans<<<dim3(8, 32, 6), 256, 0, stream>>>(W2, w2T, 2048, 512, 2048LL * 512, 512LL * 2048);
  projconv<<<(N_LAYER * M_ALLOC * 64) / 256, 256, 0, stream>>>(Pr, projT);

  // LN1 for layer 0 (later layers get it fused into ff2red_ln)
  ln_kernel<<<ROWS / 4, 256, 0, stream>>>(x, ln1g, ln1b, hbuf);

  for (int l = 0; l < N_LAYER; l++) {
    const u16* wq = wqkvT + (long long)l * 1536 * 512;
    const u16* wo = woT + (long long)l * 512 * 512;
    const u16* w1 = w1T + (long long)l * 2048 * 512;
    const u16* w2 = w2T + (long long)l * 512 * 2048;
    const u16* pj = projT + (long long)l * M_ALLOC * 64;

    // qkv_pre = h @ Wqkv^T  (8192 x 1536, K=512)
    gemm4s<0, 1, 512><<<dim3(64, 6), 512, 81920, stream>>>(hbuf, wq, big, nullptr, 1536);
    // fused rotary + diag + v-transpose (+ kmax reset)
    rotvt<<<1024, 256, 0, stream>>>((u16*)big, tsin, tcos, qrbuf, krbuf, vTbuf,
                                    diagq, diagk, kmaxu);
    // pass A: global k-max only (no dd store)
    gemm2<7, 128, 1><<<dim3(512, 3, 1), 256, 0, stream>>>(krbuf, pj, nullptr, nullptr,
        64, M_PAD, 0, 0, 0, 0.35355339f, M_PAD, BHN, kmaxu);
    // pass B: recompute + fused exp -> kfT + ksum partials
    kf_gemm<<<dim3(32, 1, 32), 384, 0, stream>>>(krbuf, pj, diagk, kmaxu, kfT, kspart);
    // ctx = kf^T @ v  split-K=4 (partials stride M_PAD)
    gemm2<5, 64, 4><<<dim3(3, 1, 128), 256, 0, stream>>>(kfT, vTbuf, part, nullptr,
        2048, 64, (long long)M_ALLOC * N_SEQ, 64LL * N_SEQ, 0, 1.0f, 64, M_PAD, nullptr);
    // ctx reduce+transpose + fused ksum reduce (bf16)
    ctxred<<<dim3(5, 32), 256, 0, stream>>>(part, ctxT, kspart, ksumb);
    // fused dd_q -> e (LDS) -> {o_raw, denom} MFMA -> o scatter
    ddq_qf_o<<<dim3(32, 1, 32), 384, 75776, stream>>>(qrbuf, pj, diagq, ksumb, ctxT, obuf);
    // x += o @ Wo^T
    gemm_small<2, 512><<<dim3(128, 8, 1), 256, 0, stream>>>(obuf, wo, x, nullptr,
        512, 0, 0);
    // LN2 -> h
    ln_kernel<<<ROWS / 4, 256, 0, stream>>>(x, ln2g + l * 512, ln2b + l * 512, hbuf);
    // ff = gelu(h @ W1^T + b1)
    gemm4s<3, 1, 512><<<dim3(64, 8), 512, 81920, stream>>>(hbuf, w1, big,
        b1 + (long long)l * 2048, 2048);
    // ff2 partials = ff @ W2^T  [split-K=2]
    gemm4s<5, 2, 2048><<<dim3(64, 2, 2), 512, 81920, stream>>>((u16*)big, w2, ff2part,
        nullptr, 512);
    // x += sum(partials) + b2; fused LN (next layer's LN1, or final LN -> d_out)
    if (l < N_LAYER - 1) {
      ff2red_ln<false, 2><<<2048, 256, 0, stream>>>(ff2part, b2 + (long long)l * 512, x,
          ln1g + (long long)(l + 1) * 512, ln1b + (long long)(l + 1) * 512, hbuf);
    } else {
      ff2red_ln<true, 2><<<2048, 256, 0, stream>>>(ff2part, b2 + (long long)l * 512, x,
          lnfg, lnfb, d_out);
    }
  }
}